// Round 6
// baseline (196.813 us; speedup 1.0000x reference)
//
#include <hip/hip_runtime.h>
#include <hip/hip_bf16.h>

#define S_LEN 2048
#define DIM_  2048
#define NH    32
#define NKV   8
#define HD    64

typedef __bf16 bf16x8 __attribute__((ext_vector_type(8)));
typedef float  f32x4  __attribute__((ext_vector_type(4)));

__device__ __forceinline__ bf16x8 pack8(float4 a, float4 b) {
  bf16x8 r;
  r[0] = (__bf16)a.x; r[1] = (__bf16)a.y; r[2] = (__bf16)a.z; r[3] = (__bf16)a.w;
  r[4] = (__bf16)b.x; r[5] = (__bf16)b.y; r[6] = (__bf16)b.z; r[7] = (__bf16)b.w;
  return r;
}

// ---------------- 128x128 GEMM, BK=64, 8 waves, fused fp32->bf16 staging ----
// Reg-staged (load-early / write-late), XOR chunk swizzle (ch ^= row&7) so the
// 128-B LDS rows are conflict-free on ds_read_b128. One barrier per K-step.
#define BK64   64
#define TILE64 8192   // 128*64 bf16

template<bool A_IS_BF16>
__device__ __forceinline__ void gemm_loop64(
    const void* Ap, const float* Bp, int row0, int col0, int lda, int ldb,
    __bf16* As, __bf16* Bs, f32x4 acc[4][2])
{
  const int tid  = threadIdx.x;
  const int lane = tid & 63;
  const int wave = tid >> 6;
  const int wr = wave >> 2, wc = wave & 3;   // 2x4 wave grid
  const int fr = lane & 15, fg = lane >> 4;
  const int srow = tid >> 2;                 // staging row 0..127
  const int sc4  = tid & 3;                  // 16-elem segment within row
  const int wch0 = (2 * sc4)     ^ (srow & 7);
  const int wch1 = (2 * sc4 + 1) ^ (srow & 7);
  const int nt = DIM_ / BK64;                // 32

  bf16x8 ar[2], br[2];

  auto loadAB = [&](int t) {
    const int k0 = t * BK64;
    if (A_IS_BF16) {
      const __bf16* A = (const __bf16*)Ap;
      const __bf16* p = A + (size_t)(row0 + srow) * lda + k0 + sc4 * 16;
      ar[0] = *(const bf16x8*)(p);
      ar[1] = *(const bf16x8*)(p + 8);
    } else {
      const float* A = (const float*)Ap;
      const float* p = A + (size_t)(row0 + srow) * lda + k0 + sc4 * 16;
      float4 f0 = ((const float4*)p)[0], f1 = ((const float4*)p)[1];
      float4 f2 = ((const float4*)p)[2], f3 = ((const float4*)p)[3];
      ar[0] = pack8(f0, f1); ar[1] = pack8(f2, f3);
    }
    const float* q = Bp + (size_t)(col0 + srow) * ldb + k0 + sc4 * 16;
    float4 g0 = ((const float4*)q)[0], g1 = ((const float4*)q)[1];
    float4 g2 = ((const float4*)q)[2], g3 = ((const float4*)q)[3];
    br[0] = pack8(g0, g1); br[1] = pack8(g2, g3);
  };
  auto writeAB = [&](int buf) {
    __bf16* a = As + buf * TILE64 + srow * 64;
    __bf16* b = Bs + buf * TILE64 + srow * 64;
    *(bf16x8*)(a + wch0 * 8) = ar[0];
    *(bf16x8*)(a + wch1 * 8) = ar[1];
    *(bf16x8*)(b + wch0 * 8) = br[0];
    *(bf16x8*)(b + wch1 * 8) = br[1];
  };

  loadAB(0);
  writeAB(0);
  __syncthreads();

  for (int t = 0; t < nt; ++t) {
    const int cur = t & 1;
    loadAB(t + 1 < nt ? t + 1 : t);   // clamped prefetch (last iter harmless)
#pragma unroll
    for (int kk = 0; kk < 2; ++kk) {
      bf16x8 a[4], b[2];
#pragma unroll
      for (int mi = 0; mi < 4; ++mi) {
        int R = wr * 64 + mi * 16 + fr;
        a[mi] = *(const bf16x8*)(As + cur * TILE64 + R * 64 + (((kk * 4 + fg) ^ (fr & 7)) * 8));
      }
#pragma unroll
      for (int ni = 0; ni < 2; ++ni) {
        int R = wc * 32 + ni * 16 + fr;
        b[ni] = *(const bf16x8*)(Bs + cur * TILE64 + R * 64 + (((kk * 4 + fg) ^ (fr & 7)) * 8));
      }
#pragma unroll
      for (int mi = 0; mi < 4; ++mi)
#pragma unroll
        for (int ni = 0; ni < 2; ++ni)
          acc[mi][ni] = __builtin_amdgcn_mfma_f32_16x16x32_bf16(a[mi], b[ni], acc[mi][ni], 0, 0, 0);
    }
    writeAB(cur ^ 1);   // next tile -> back buffer (no one reads it this iter)
    __syncthreads();
  }
}

// ---------------- QKV projection: reads x, wq/wk/wv fp32 directly -----------
__global__ __launch_bounds__(512) void qkv_gemm(
    const float* __restrict__ x,  const float* __restrict__ wq,
    const float* __restrict__ wk, const float* __restrict__ wv,
    __bf16* __restrict__ q_buf, __bf16* __restrict__ k_buf, __bf16* __restrict__ v_buf)
{
  __shared__ __bf16 As[2 * TILE64];
  __shared__ __bf16 Bs[2 * TILE64];
  const int lane = threadIdx.x & 63;
  const int wave = threadIdx.x >> 6;
  const int wr = wave >> 2, wc = wave & 3;
  const int fr = lane & 15, fg = lane >> 4;
  const int row0 = blockIdx.y * 128;
  const int bx = blockIdx.x;
  const int col0 = bx * 128;

  const float* wbase; int noff;
  if (bx < 16)      { wbase = wq; noff = 0; }
  else if (bx < 20) { wbase = wk; noff = 2048; }
  else              { wbase = wv; noff = 2560; }

  f32x4 acc[4][2] = {};
  gemm_loop64<false>(x, wbase, row0, col0 - noff, DIM_, DIM_, As, Bs, acc);

  const int rowg0 = row0 + wr * 64;
  const int colg0 = col0 + wc * 32;
#pragma unroll
  for (int mi = 0; mi < 4; ++mi) {
#pragma unroll
    for (int ni = 0; ni < 2; ++ni) {
#pragma unroll
      for (int j = 0; j < 4; ++j) {
        int row = rowg0 + mi * 16 + fg * 4 + j;
        int col = colg0 + ni * 16 + fr;
        float v = acc[mi][ni][j];
        if (col < 2048) {
          int h = col >> 6, d = col & 63;
          q_buf[((size_t)h * S_LEN + row) * HD + d] = (__bf16)v;
        } else if (col < 2560) {
          int c = col - 2048, g = c >> 6, d = c & 63;
          k_buf[((size_t)g * S_LEN + row) * HD + d] = (__bf16)v;
        } else {
          int c = col - 2560, g = c >> 6, d = c & 63;
          v_buf[((size_t)g * HD + d) * S_LEN + row] = (__bf16)v;  // transposed
        }
      }
    }
  }
}

// ---------------- Output projection: attn(bf16) @ wo(fp32)^T -> fp32 --------
__global__ __launch_bounds__(512) void oproj_gemm(
    const __bf16* __restrict__ attn_buf, const float* __restrict__ wo,
    float* __restrict__ out)
{
  __shared__ __bf16 As[2 * TILE64];
  __shared__ __bf16 Bs[2 * TILE64];
  const int lane = threadIdx.x & 63;
  const int wave = threadIdx.x >> 6;
  const int wr = wave >> 2, wc = wave & 3;
  const int fr = lane & 15, fg = lane >> 4;
  const int row0 = blockIdx.y * 128;
  const int col0 = blockIdx.x * 128;

  f32x4 acc[4][2] = {};
  gemm_loop64<true>(attn_buf, wo, row0, col0, DIM_, DIM_, As, Bs, acc);

  const int rowg0 = row0 + wr * 64;
  const int colg0 = col0 + wc * 32;
#pragma unroll
  for (int mi = 0; mi < 4; ++mi)
#pragma unroll
    for (int ni = 0; ni < 2; ++ni)
#pragma unroll
      for (int j = 0; j < 4; ++j) {
        int row = rowg0 + mi * 16 + fg * 4 + j;
        int col = colg0 + ni * 16 + fr;
        out[(size_t)row * DIM_ + col] = acc[mi][ni][j];
      }
}

// ---------------- RoPE on K only (in place, bf16); Q fused into attn --------
__global__ __launch_bounds__(256) void rope_k(
    __bf16* __restrict__ k_buf, const float* __restrict__ fc)
{
  int idx = blockIdx.x * 256 + threadIdx.x;  // NKV*S*32 threads
  int i    = idx & 31;
  int sp   = (idx >> 5) & (S_LEN - 1);
  int g    = idx >> 16;                      // S*32 = 65536 per head
  __bf16* buf = k_buf + ((size_t)g * S_LEN + sp) * HD;
  float c = fc[(sp * 32 + i) * 2 + 0];
  float s = fc[(sp * 32 + i) * 2 + 1];
  float x1 = (float)buf[2 * i], x2 = (float)buf[2 * i + 1];
  buf[2 * i + 0] = (__bf16)(x1 * c - x2 * s);
  buf[2 * i + 1] = (__bf16)(x1 * s + x2 * c);
}

// ---------------- Flash attention (causal, GQA, swapped-QK, shared KV) ------
// Grid: (S/128, NH). Block: 8 waves; wave w owns q-rows [qt*128+w*16, +16).
// Q-RoPE applied in-register at load (pairs are lane-local in the A-frag).
__global__ __launch_bounds__(512) void attn_kernel(
    const __bf16* __restrict__ q_buf, const __bf16* __restrict__ k_buf,
    const __bf16* __restrict__ v_buf, const float* __restrict__ fc,
    __bf16* __restrict__ attn_buf)
{
  __shared__ __align__(16) __bf16 Ks[2][64 * 64];   // 2 x 8 KB
  __shared__ __align__(16) __bf16 Vs[2][64 * 64];   // 2 x 8 KB (V^T: [d][kv])
  __shared__ __align__(16) __bf16 lds_p[8][16][72]; // per-wave P slab

  const int tid  = threadIdx.x;
  const int lane = tid & 63;
  const int wave = tid >> 6;
  const int qt = (int)gridDim.x - 1 - (int)blockIdx.x;  // long blocks first
  const int h = blockIdx.y;
  const int g = h >> 2;             // NREP = 4
  const int r0 = qt * 128 + wave * 16;
  const int lrow = lane & 15;
  const int lgrp = lane >> 4;
  const int lk = lgrp * 8;

  const __bf16* qh = q_buf + (size_t)h * S_LEN * HD;
  const __bf16* kh = k_buf + (size_t)g * S_LEN * HD;
  const __bf16* vh = v_buf + (size_t)g * HD * S_LEN;

  const int sr   = tid >> 3;            // staging row 0..63
  const int scol = tid & 7;             // source 16B chunk
  const int dcol = scol ^ (sr & 7);     // swizzled dest chunk

  // ---- load Q fragment + apply RoPE in-register ----
  bf16x8 qa[2];
  const float* fcrow = fc + (size_t)(r0 + lrow) * 64;   // [32 pairs][cos,sin]
#pragma unroll
  for (int kk = 0; kk < 2; ++kk) {
    qa[kk] = *(const bf16x8*)(qh + (size_t)(r0 + lrow) * HD + kk * 32 + lk);
    float4 cs0 = *(const float4*)(fcrow + (kk * 16 + lgrp * 4) * 2);
    float4 cs1 = *(const float4*)(fcrow + (kk * 16 + lgrp * 4) * 2 + 4);
    float cc[4] = {cs0.x, cs0.z, cs1.x, cs1.z};
    float ss[4] = {cs0.y, cs0.w, cs1.y, cs1.w};
#pragma unroll
    for (int pr = 0; pr < 4; ++pr) {
      float x1 = (float)qa[kk][2 * pr], x2 = (float)qa[kk][2 * pr + 1];
      qa[kk][2 * pr]     = (__bf16)(x1 * cc[pr] - x2 * ss[pr]);
      qa[kk][2 * pr + 1] = (__bf16)(x1 * ss[pr] + x2 * cc[pr]);
    }
  }

  const float KS = 0.125f * 1.44269504088896f;  // scale * log2(e)
  float m_col = -3.0e38f, l_col = 0.f;
  f32x4 oacc[4] = {};

  const int nt = 2 * qt + 2;

  {
    uint4 k0 = *(const uint4*)(kh + (size_t)sr * HD + scol * 8);
    uint4 v0 = *(const uint4*)(vh + (size_t)sr * S_LEN + scol * 8);
    *(uint4*)(&Ks[0][sr * 64 + dcol * 8]) = k0;
    *(uint4*)(&Vs[0][sr * 64 + dcol * 8]) = v0;
  }
  __syncthreads();

  for (int t = 0; t < nt; ++t) {
    const int cur = t & 1;
    const int t0 = t * 64;

    const int tn0 = (t + 1 < nt ? t + 1 : t) * 64;
    uint4 kreg = *(const uint4*)(kh + (size_t)(tn0 + sr) * HD + scol * 8);
    uint4 vreg = *(const uint4*)(vh + (size_t)sr * S_LEN + tn0 + scol * 8);

    const int dmax = r0 + 15 - t0;
    if (dmax >= 0) {
      f32x4 sc[4] = {};
      const int cmax = dmax >> 4;
      __builtin_amdgcn_s_setprio(1);
#pragma unroll
      for (int c = 0; c < 4; ++c) {
        if (c <= cmax) {
#pragma unroll
          for (int kk = 0; kk < 2; ++kk) {
            bf16x8 ka = *(const bf16x8*)(
                &Ks[cur][(c * 16 + lrow) * 64 + (((kk * 4 + lgrp) ^ (lrow & 7)) * 8)]);
            sc[c] = __builtin_amdgcn_mfma_f32_16x16x32_bf16(ka, qa[kk], sc[c], 0, 0, 0);
          }
        }
      }
      __builtin_amdgcn_s_setprio(0);

      float p[16];
      const int q = r0 + lrow;
      if (t0 + 63 <= r0) {
#pragma unroll
        for (int c = 0; c < 4; ++c)
#pragma unroll
          for (int j = 0; j < 4; ++j)
            p[c * 4 + j] = sc[c][j] * KS;
      } else {
#pragma unroll
        for (int c = 0; c < 4; ++c)
#pragma unroll
          for (int j = 0; j < 4; ++j) {
            int kv = t0 + c * 16 + lgrp * 4 + j;
            p[c * 4 + j] = (kv <= q) ? sc[c][j] * KS : -3.0e38f;
          }
      }

      float m8[8], m4[4];
#pragma unroll
      for (int i = 0; i < 8; ++i) m8[i] = fmaxf(p[i], p[i + 8]);
#pragma unroll
      for (int i = 0; i < 4; ++i) m4[i] = fmaxf(m8[i], m8[i + 4]);
      float mx = fmaxf(fmaxf(m4[0], m4[1]), fmaxf(m4[2], m4[3]));
      mx = fmaxf(mx, __shfl_xor(mx, 16, 64));
      mx = fmaxf(mx, __shfl_xor(mx, 32, 64));

      if (__all(mx <= m_col + 8.f)) {
        // defer: alpha == 1
      } else {
        float nm = fmaxf(m_col, mx);
        float alpha = __builtin_amdgcn_exp2f(m_col - nm);
        m_col = nm;
        float ar[4];
#pragma unroll
        for (int j = 0; j < 4; ++j)
          ar[j] = __shfl(alpha, lgrp * 4 + j, 64);
#pragma unroll
        for (int nf = 0; nf < 4; ++nf)
#pragma unroll
          for (int j = 0; j < 4; ++j)
            oacc[nf][j] *= ar[j];
        l_col *= alpha;
      }

#pragma unroll
      for (int i = 0; i < 16; ++i)
        p[i] = __builtin_amdgcn_exp2f(p[i] - m_col);
      float s8[8], s4[4];
#pragma unroll
      for (int i = 0; i < 8; ++i) s8[i] = p[i] + p[i + 8];
#pragma unroll
      for (int i = 0; i < 4; ++i) s4[i] = s8[i] + s8[i + 4];
      float rs = (s4[0] + s4[1]) + (s4[2] + s4[3]);
      rs += __shfl_xor(rs, 16, 64);
      rs += __shfl_xor(rs, 32, 64);
      l_col += rs;

#pragma unroll
      for (int c = 0; c < 4; ++c)
#pragma unroll
        for (int e = 0; e < 2; ++e) {
          union { __bf16 hh[2]; unsigned u; } pk;
          pk.hh[0] = (__bf16)p[c * 4 + 2 * e];
          pk.hh[1] = (__bf16)p[c * 4 + 2 * e + 1];
          *(unsigned*)&lds_p[wave][lrow][c * 16 + lgrp * 4 + 2 * e] = pk.u;
        }
      asm volatile("s_waitcnt lgkmcnt(0)" ::: "memory");

      bf16x8 pa0 = *(const bf16x8*)&lds_p[wave][lrow][lk];
      __builtin_amdgcn_s_setprio(1);
#pragma unroll
      for (int nf = 0; nf < 4; ++nf) {
        bf16x8 vb = *(const bf16x8*)(
            &Vs[cur][(nf * 16 + lrow) * 64 + ((lgrp ^ (lrow & 7)) * 8)]);
        oacc[nf] = __builtin_amdgcn_mfma_f32_16x16x32_bf16(pa0, vb, oacc[nf], 0, 0, 0);
      }
      __builtin_amdgcn_s_setprio(0);
      if (dmax >= 32) {
        bf16x8 pa1 = *(const bf16x8*)&lds_p[wave][lrow][32 + lk];
        __builtin_amdgcn_s_setprio(1);
#pragma unroll
        for (int nf = 0; nf < 4; ++nf) {
          bf16x8 vb = *(const bf16x8*)(
              &Vs[cur][(nf * 16 + lrow) * 64 + (((4 + lgrp) ^ (lrow & 7)) * 8)]);
          oacc[nf] = __builtin_amdgcn_mfma_f32_16x16x32_bf16(pa1, vb, oacc[nf], 0, 0, 0);
        }
        __builtin_amdgcn_s_setprio(0);
      }
    }

    *(uint4*)(&Ks[cur ^ 1][sr * 64 + dcol * 8]) = kreg;
    *(uint4*)(&Vs[cur ^ 1][sr * 64 + dcol * 8]) = vreg;
    __syncthreads();
  }

  float rlr[4];
#pragma unroll
  for (int j = 0; j < 4; ++j)
    rlr[j] = 1.0f / __shfl(l_col, lgrp * 4 + j, 64);
#pragma unroll
  for (int nf = 0; nf < 4; ++nf)
#pragma unroll
    for (int j = 0; j < 4; ++j) {
      int row = r0 + lgrp * 4 + j;
      attn_buf[(size_t)row * (NH * HD) + h * HD + nf * 16 + lrow] =
          (__bf16)(oacc[nf][j] * rlr[j]);
    }
}

extern "C" void kernel_launch(void* const* d_in, const int* in_sizes, int n_in,
                              void* d_out, int out_size, void* d_ws, size_t ws_size,
                              hipStream_t stream)
{
  const float* x  = (const float*)d_in[0];
  const float* wq = (const float*)d_in[1];
  const float* wk = (const float*)d_in[2];
  const float* wv = (const float*)d_in[3];
  const float* wo = (const float*)d_in[4];
  const float* fc = (const float*)d_in[5];
  float* out = (float*)d_out;

  char* ws = (char*)d_ws;
  __bf16* q_buf    = (__bf16*)(ws);                       //  8 MB [NH][S][HD]
  __bf16* k_buf    = (__bf16*)(ws +  8u * 1024 * 1024);   //  2 MB [NKV][S][HD]
  __bf16* v_buf    = (__bf16*)(ws + 10u * 1024 * 1024);   //  2 MB [NKV][HD][S]
  __bf16* attn_buf = (__bf16*)(ws + 12u * 1024 * 1024);   //  8 MB [S][NH*HD]

  qkv_gemm<<<dim3(24, 16), 512, 0, stream>>>(x, wq, wk, wv, q_buf, k_buf, v_buf);
  rope_k<<<dim3(2048), 256, 0, stream>>>(k_buf, fc);
  attn_kernel<<<dim3(16, 32), 512, 0, stream>>>(q_buf, k_buf, v_buf, fc, attn_buf);
  oproj_gemm<<<dim3(16, 16), 512, 0, stream>>>(attn_buf, wo, out);
}

// Round 7
// 173.108 us; speedup vs baseline: 1.1369x; 1.1369x over previous
//
#include <hip/hip_runtime.h>
#include <hip/hip_bf16.h>

#define S_LEN 2048
#define DIM_  2048
#define NH    32
#define NKV   8
#define HD    64

typedef __bf16 bf16x8 __attribute__((ext_vector_type(8)));
typedef __bf16 bf16x4 __attribute__((ext_vector_type(4)));
typedef float  f32x4  __attribute__((ext_vector_type(4)));

#define AS_GLOBAL(p) ((const __attribute__((address_space(1))) void*)(p))
#define AS_LDS(p)    ((__attribute__((address_space(3))) void*)(p))

__device__ __forceinline__ bf16x8 pack8(float4 a, float4 b) {
  bf16x8 r;
  r[0] = (__bf16)a.x; r[1] = (__bf16)a.y; r[2] = (__bf16)a.z; r[3] = (__bf16)a.w;
  r[4] = (__bf16)b.x; r[5] = (__bf16)b.y; r[6] = (__bf16)b.z; r[7] = (__bf16)b.w;
  return r;
}

// ---------------- fp32 -> bf16 conversion (x, wq|wk|wv concat) --------------
// Grid 10240 x 256: one float4 per thread.
__global__ __launch_bounds__(256) void cvt_xw(
    const float* __restrict__ x,  const float* __restrict__ wq,
    const float* __restrict__ wk, const float* __restrict__ wv,
    __bf16* __restrict__ xb, __bf16* __restrict__ wb)
{
  size_t i = (size_t)blockIdx.x * 256 + threadIdx.x;
  const float* src; __bf16* dst; size_t off;
  if (i < 1048576)      { src = x;  dst = xb;            off = i; }
  else if (i < 2097152) { src = wq; dst = wb;            off = i - 1048576; }
  else if (i < 2359296) { src = wk; dst = wb + 4194304;  off = i - 2097152; }
  else                  { src = wv; dst = wb + 5242880;  off = i - 2359296; }
  float4 f = ((const float4*)src)[off];
  bf16x4 r;
  r[0] = (__bf16)f.x; r[1] = (__bf16)f.y; r[2] = (__bf16)f.z; r[3] = (__bf16)f.w;
  ((bf16x4*)dst)[off] = r;
}

// ---------------- 128x128 bf16 GEMM, BK=32, 8 waves, global_load_lds --------
#define BK 32
#define TILE_ELEMS 4096   // 128*32

// 512 threads stage one 128x32 bf16 tile (8 KB): one 16B chunk each.
__device__ __forceinline__ void stage_tile(
    const __bf16* __restrict__ g, int row0, int k0, int ld, __bf16* lds)
{
  const int tid = threadIdx.x;
  int off = tid * 16;        // byte offset in 8 KB tile
  int r = off >> 6;          // 64 B per row (32 bf16)
  int c = (off & 63) >> 1;   // bf16 col
  __builtin_amdgcn_global_load_lds(
      AS_GLOBAL(g + (size_t)(row0 + r) * ld + k0 + c),
      AS_LDS(lds + (tid >> 6) * 512),   // wave-uniform base + lane*16
      16, 0, 0);
}

__device__ __forceinline__ void gemm_mainloop(
    const __bf16* __restrict__ A, const __bf16* __restrict__ B,
    int row0, int col0, int lda, int ldb, int nt,
    __bf16* As, __bf16* Bs, f32x4 acc[4][2])
{
  const int lane = threadIdx.x & 63;
  const int wave = threadIdx.x >> 6;
  const int wr = wave >> 2, wc = wave & 3;   // 2x4 wave grid
  const int fr = lane & 15, fg = lane >> 4;

  stage_tile(A, row0, 0, lda, As);
  stage_tile(B, col0, 0, ldb, Bs);

  for (int t = 0; t < nt; ++t) {
    const int cur = t & 1;
    if (t + 1 < nt) {
      stage_tile(A, row0, (t + 1) * BK, lda, As + (cur ^ 1) * TILE_ELEMS);
      stage_tile(B, col0, (t + 1) * BK, ldb, Bs + (cur ^ 1) * TILE_ELEMS);
    }
    __syncthreads();
    bf16x8 a[4], b[2];
#pragma unroll
    for (int mi = 0; mi < 4; ++mi)
      a[mi] = *(const bf16x8*)(As + cur * TILE_ELEMS + (wr * 64 + mi * 16 + fr) * 32 + fg * 8);
#pragma unroll
    for (int ni = 0; ni < 2; ++ni)
      b[ni] = *(const bf16x8*)(Bs + cur * TILE_ELEMS + (wc * 32 + ni * 16 + fr) * 32 + fg * 8);
#pragma unroll
    for (int mi = 0; mi < 4; ++mi)
#pragma unroll
      for (int ni = 0; ni < 2; ++ni)
        acc[mi][ni] = __builtin_amdgcn_mfma_f32_16x16x32_bf16(a[mi], b[ni], acc[mi][ni], 0, 0, 0);
    __syncthreads();
  }
}

// ---------------- QKV projection (bf16 inputs) ------------------------------
// Grid 384 blocks, XCD-chunk swizzled (384 % 8 == 0 -> bijective).
__global__ __launch_bounds__(512) void qkv_gemm(
    const __bf16* __restrict__ xb, const __bf16* __restrict__ wb,
    __bf16* __restrict__ q_buf, __bf16* __restrict__ k_buf, __bf16* __restrict__ v_buf)
{
  __shared__ __bf16 As[2 * TILE_ELEMS];
  __shared__ __bf16 Bs[2 * TILE_ELEMS];
  const int lane = threadIdx.x & 63;
  const int wave = threadIdx.x >> 6;
  const int wr = wave >> 2, wc = wave & 3;
  const int fr = lane & 15, fg = lane >> 4;

  // XCD swizzle: contiguous 48-block chunks (2 row-panels) per XCD
  int lid = blockIdx.x;                    // 0..383, x-fastest = col-fastest
  int swz = (lid & 7) * 48 + (lid >> 3);
  const int row0 = (swz / 24) * 128;
  const int col0 = (swz % 24) * 128;

  f32x4 acc[4][2] = {};
  gemm_mainloop(xb, wb, row0, col0, DIM_, DIM_, DIM_ / BK, As, Bs, acc);

  const int rowg0 = row0 + wr * 64;
  const int colg0 = col0 + wc * 32;
#pragma unroll
  for (int mi = 0; mi < 4; ++mi) {
#pragma unroll
    for (int ni = 0; ni < 2; ++ni) {
#pragma unroll
      for (int j = 0; j < 4; ++j) {
        int row = rowg0 + mi * 16 + fg * 4 + j;
        int col = colg0 + ni * 16 + fr;
        float v = acc[mi][ni][j];
        if (col < 2048) {
          int h = col >> 6, d = col & 63;
          q_buf[((size_t)h * S_LEN + row) * HD + d] = (__bf16)v;
        } else if (col < 2560) {
          int c = col - 2048, g = c >> 6, d = c & 63;
          k_buf[((size_t)g * S_LEN + row) * HD + d] = (__bf16)v;
        } else {
          int c = col - 2560, g = c >> 6, d = c & 63;
          v_buf[((size_t)g * HD + d) * S_LEN + row] = (__bf16)v;  // transposed
        }
      }
    }
  }
}

// ---------------- Output projection: attn(bf16) @ wo(fp32)^T -> fp32 --------
// Reg-staged BK=64 with fused fp32->bf16 for wo (read once per row-block).
#define BK64   64
#define TILE64 8192   // 128*64 bf16

__global__ __launch_bounds__(512) void oproj_gemm(
    const __bf16* __restrict__ attn_buf, const float* __restrict__ wo,
    float* __restrict__ out)
{
  __shared__ __bf16 As[2 * TILE64];
  __shared__ __bf16 Bs[2 * TILE64];
  const int tid  = threadIdx.x;
  const int lane = tid & 63;
  const int wave = tid >> 6;
  const int wr = wave >> 2, wc = wave & 3;
  const int fr = lane & 15, fg = lane >> 4;

  // XCD swizzle: 256 blocks -> 32-block chunks (2 row-panels x 16 cols)
  int lid = blockIdx.x;
  int swz = (lid & 7) * 32 + (lid >> 3);
  const int row0 = (swz >> 4) * 128;
  const int col0 = (swz & 15) * 128;

  const int srow = tid >> 2;
  const int sc4  = tid & 3;
  const int wch0 = (2 * sc4)     ^ (srow & 7);
  const int wch1 = (2 * sc4 + 1) ^ (srow & 7);
  const int nt = DIM_ / BK64;

  bf16x8 ar[2], br[2];
  auto loadAB = [&](int t) {
    const int k0 = t * BK64;
    const __bf16* p = attn_buf + (size_t)(row0 + srow) * DIM_ + k0 + sc4 * 16;
    ar[0] = *(const bf16x8*)(p);
    ar[1] = *(const bf16x8*)(p + 8);
    const float* q = wo + (size_t)(col0 + srow) * DIM_ + k0 + sc4 * 16;
    float4 g0 = ((const float4*)q)[0], g1 = ((const float4*)q)[1];
    float4 g2 = ((const float4*)q)[2], g3 = ((const float4*)q)[3];
    br[0] = pack8(g0, g1); br[1] = pack8(g2, g3);
  };
  auto writeAB = [&](int buf) {
    __bf16* a = As + buf * TILE64 + srow * 64;
    __bf16* b = Bs + buf * TILE64 + srow * 64;
    *(bf16x8*)(a + wch0 * 8) = ar[0];
    *(bf16x8*)(a + wch1 * 8) = ar[1];
    *(bf16x8*)(b + wch0 * 8) = br[0];
    *(bf16x8*)(b + wch1 * 8) = br[1];
  };

  f32x4 acc[4][2] = {};
  loadAB(0);
  writeAB(0);
  __syncthreads();

  for (int t = 0; t < nt; ++t) {
    const int cur = t & 1;
    loadAB(t + 1 < nt ? t + 1 : t);
#pragma unroll
    for (int kk = 0; kk < 2; ++kk) {
      bf16x8 a[4], b[2];
#pragma unroll
      for (int mi = 0; mi < 4; ++mi) {
        int R = wr * 64 + mi * 16 + fr;
        a[mi] = *(const bf16x8*)(As + cur * TILE64 + R * 64 + (((kk * 4 + fg) ^ (fr & 7)) * 8));
      }
#pragma unroll
      for (int ni = 0; ni < 2; ++ni) {
        int R = wc * 32 + ni * 16 + fr;
        b[ni] = *(const bf16x8*)(Bs + cur * TILE64 + R * 64 + (((kk * 4 + fg) ^ (fr & 7)) * 8));
      }
#pragma unroll
      for (int mi = 0; mi < 4; ++mi)
#pragma unroll
        for (int ni = 0; ni < 2; ++ni)
          acc[mi][ni] = __builtin_amdgcn_mfma_f32_16x16x32_bf16(a[mi], b[ni], acc[mi][ni], 0, 0, 0);
    }
    writeAB(cur ^ 1);
    __syncthreads();
  }

  const int rowg0 = row0 + wr * 64;
  const int colg0 = col0 + wc * 32;
#pragma unroll
  for (int mi = 0; mi < 4; ++mi)
#pragma unroll
    for (int ni = 0; ni < 2; ++ni)
#pragma unroll
      for (int j = 0; j < 4; ++j) {
        int row = rowg0 + mi * 16 + fg * 4 + j;
        int col = colg0 + ni * 16 + fr;
        out[(size_t)row * DIM_ + col] = acc[mi][ni][j];
      }
}

// ---------------- RoPE on K only (in place, bf16); Q fused into attn --------
__global__ __launch_bounds__(256) void rope_k(
    __bf16* __restrict__ k_buf, const float* __restrict__ fc)
{
  int idx = blockIdx.x * 256 + threadIdx.x;  // NKV*S*32 threads
  int i    = idx & 31;
  int sp   = (idx >> 5) & (S_LEN - 1);
  int g    = idx >> 16;
  __bf16* buf = k_buf + ((size_t)g * S_LEN + sp) * HD;
  float c = fc[(sp * 32 + i) * 2 + 0];
  float s = fc[(sp * 32 + i) * 2 + 1];
  float x1 = (float)buf[2 * i], x2 = (float)buf[2 * i + 1];
  buf[2 * i + 0] = (__bf16)(x1 * c - x2 * s);
  buf[2 * i + 1] = (__bf16)(x1 * s + x2 * c);
}

// ---------------- Flash attention (causal, GQA, swapped-QK, shared KV) ------
__global__ __launch_bounds__(512) void attn_kernel(
    const __bf16* __restrict__ q_buf, const __bf16* __restrict__ k_buf,
    const __bf16* __restrict__ v_buf, const float* __restrict__ fc,
    __bf16* __restrict__ attn_buf)
{
  __shared__ __align__(16) __bf16 Ks[2][64 * 64];   // 2 x 8 KB
  __shared__ __align__(16) __bf16 Vs[2][64 * 64];   // 2 x 8 KB (V^T: [d][kv])
  __shared__ __align__(16) __bf16 lds_p[8][16][72]; // per-wave P slab

  const int tid  = threadIdx.x;
  const int lane = tid & 63;
  const int wave = tid >> 6;
  const int qt = (int)gridDim.x - 1 - (int)blockIdx.x;  // long blocks first
  const int h = blockIdx.y;
  const int g = h >> 2;             // NREP = 4
  const int r0 = qt * 128 + wave * 16;
  const int lrow = lane & 15;
  const int lgrp = lane >> 4;
  const int lk = lgrp * 8;

  const __bf16* qh = q_buf + (size_t)h * S_LEN * HD;
  const __bf16* kh = k_buf + (size_t)g * S_LEN * HD;
  const __bf16* vh = v_buf + (size_t)g * HD * S_LEN;

  const int sr   = tid >> 3;            // staging row 0..63
  const int scol = tid & 7;             // source 16B chunk
  const int dcol = scol ^ (sr & 7);     // swizzled dest chunk

  // ---- load Q fragment + apply RoPE in-register ----
  bf16x8 qa[2];
  const float* fcrow = fc + (size_t)(r0 + lrow) * 64;
#pragma unroll
  for (int kk = 0; kk < 2; ++kk) {
    qa[kk] = *(const bf16x8*)(qh + (size_t)(r0 + lrow) * HD + kk * 32 + lk);
    float4 cs0 = *(const float4*)(fcrow + (kk * 16 + lgrp * 4) * 2);
    float4 cs1 = *(const float4*)(fcrow + (kk * 16 + lgrp * 4) * 2 + 4);
    float cc[4] = {cs0.x, cs0.z, cs1.x, cs1.z};
    float ss[4] = {cs0.y, cs0.w, cs1.y, cs1.w};
#pragma unroll
    for (int pr = 0; pr < 4; ++pr) {
      float x1 = (float)qa[kk][2 * pr], x2 = (float)qa[kk][2 * pr + 1];
      qa[kk][2 * pr]     = (__bf16)(x1 * cc[pr] - x2 * ss[pr]);
      qa[kk][2 * pr + 1] = (__bf16)(x1 * ss[pr] + x2 * cc[pr]);
    }
  }

  const float KS = 0.125f * 1.44269504088896f;  // scale * log2(e)
  float m_col = -3.0e38f, l_col = 0.f;
  f32x4 oacc[4] = {};

  const int nt = 2 * qt + 2;

  {
    uint4 k0 = *(const uint4*)(kh + (size_t)sr * HD + scol * 8);
    uint4 v0 = *(const uint4*)(vh + (size_t)sr * S_LEN + scol * 8);
    *(uint4*)(&Ks[0][sr * 64 + dcol * 8]) = k0;
    *(uint4*)(&Vs[0][sr * 64 + dcol * 8]) = v0;
  }
  __syncthreads();

  for (int t = 0; t < nt; ++t) {
    const int cur = t & 1;
    const int t0 = t * 64;

    const int tn0 = (t + 1 < nt ? t + 1 : t) * 64;
    uint4 kreg = *(const uint4*)(kh + (size_t)(tn0 + sr) * HD + scol * 8);
    uint4 vreg = *(const uint4*)(vh + (size_t)sr * S_LEN + tn0 + scol * 8);

    const int dmax = r0 + 15 - t0;
    if (dmax >= 0) {
      f32x4 sc[4] = {};
      const int cmax = dmax >> 4;
      __builtin_amdgcn_s_setprio(1);
#pragma unroll
      for (int c = 0; c < 4; ++c) {
        if (c <= cmax) {
#pragma unroll
          for (int kk = 0; kk < 2; ++kk) {
            bf16x8 ka = *(const bf16x8*)(
                &Ks[cur][(c * 16 + lrow) * 64 + (((kk * 4 + lgrp) ^ (lrow & 7)) * 8)]);
            sc[c] = __builtin_amdgcn_mfma_f32_16x16x32_bf16(ka, qa[kk], sc[c], 0, 0, 0);
          }
        }
      }
      __builtin_amdgcn_s_setprio(0);

      float p[16];
      const int q = r0 + lrow;
      if (t0 + 63 <= r0) {
#pragma unroll
        for (int c = 0; c < 4; ++c)
#pragma unroll
          for (int j = 0; j < 4; ++j)
            p[c * 4 + j] = sc[c][j] * KS;
      } else {
#pragma unroll
        for (int c = 0; c < 4; ++c)
#pragma unroll
          for (int j = 0; j < 4; ++j) {
            int kv = t0 + c * 16 + lgrp * 4 + j;
            p[c * 4 + j] = (kv <= q) ? sc[c][j] * KS : -3.0e38f;
          }
      }

      float m8[8], m4[4];
#pragma unroll
      for (int i = 0; i < 8; ++i) m8[i] = fmaxf(p[i], p[i + 8]);
#pragma unroll
      for (int i = 0; i < 4; ++i) m4[i] = fmaxf(m8[i], m8[i + 4]);
      float mx = fmaxf(fmaxf(m4[0], m4[1]), fmaxf(m4[2], m4[3]));
      mx = fmaxf(mx, __shfl_xor(mx, 16, 64));
      mx = fmaxf(mx, __shfl_xor(mx, 32, 64));

      if (__all(mx <= m_col + 8.f)) {
        // defer: alpha == 1
      } else {
        float nm = fmaxf(m_col, mx);
        float alpha = __builtin_amdgcn_exp2f(m_col - nm);
        m_col = nm;
        float ar[4];
#pragma unroll
        for (int j = 0; j < 4; ++j)
          ar[j] = __shfl(alpha, lgrp * 4 + j, 64);
#pragma unroll
        for (int nf = 0; nf < 4; ++nf)
#pragma unroll
          for (int j = 0; j < 4; ++j)
            oacc[nf][j] *= ar[j];
        l_col *= alpha;
      }

#pragma unroll
      for (int i = 0; i < 16; ++i)
        p[i] = __builtin_amdgcn_exp2f(p[i] - m_col);
      float s8[8], s4[4];
#pragma unroll
      for (int i = 0; i < 8; ++i) s8[i] = p[i] + p[i + 8];
#pragma unroll
      for (int i = 0; i < 4; ++i) s4[i] = s8[i] + s8[i + 4];
      float rs = (s4[0] + s4[1]) + (s4[2] + s4[3]);
      rs += __shfl_xor(rs, 16, 64);
      rs += __shfl_xor(rs, 32, 64);
      l_col += rs;

#pragma unroll
      for (int c = 0; c < 4; ++c)
#pragma unroll
        for (int e = 0; e < 2; ++e) {
          union { __bf16 hh[2]; unsigned u; } pk;
          pk.hh[0] = (__bf16)p[c * 4 + 2 * e];
          pk.hh[1] = (__bf16)p[c * 4 + 2 * e + 1];
          *(unsigned*)&lds_p[wave][lrow][c * 16 + lgrp * 4 + 2 * e] = pk.u;
        }
      asm volatile("s_waitcnt lgkmcnt(0)" ::: "memory");

      bf16x8 pa0 = *(const bf16x8*)&lds_p[wave][lrow][lk];
      __builtin_amdgcn_s_setprio(1);
#pragma unroll
      for (int nf = 0; nf < 4; ++nf) {
        bf16x8 vb = *(const bf16x8*)(
            &Vs[cur][(nf * 16 + lrow) * 64 + ((lgrp ^ (lrow & 7)) * 8)]);
        oacc[nf] = __builtin_amdgcn_mfma_f32_16x16x32_bf16(pa0, vb, oacc[nf], 0, 0, 0);
      }
      __builtin_amdgcn_s_setprio(0);
      if (dmax >= 32) {
        bf16x8 pa1 = *(const bf16x8*)&lds_p[wave][lrow][32 + lk];
        __builtin_amdgcn_s_setprio(1);
#pragma unroll
        for (int nf = 0; nf < 4; ++nf) {
          bf16x8 vb = *(const bf16x8*)(
              &Vs[cur][(nf * 16 + lrow) * 64 + (((4 + lgrp) ^ (lrow & 7)) * 8)]);
          oacc[nf] = __builtin_amdgcn_mfma_f32_16x16x32_bf16(pa1, vb, oacc[nf], 0, 0, 0);
        }
        __builtin_amdgcn_s_setprio(0);
      }
    }

    *(uint4*)(&Ks[cur ^ 1][sr * 64 + dcol * 8]) = kreg;
    *(uint4*)(&Vs[cur ^ 1][sr * 64 + dcol * 8]) = vreg;
    __syncthreads();
  }

  float rlr[4];
#pragma unroll
  for (int j = 0; j < 4; ++j)
    rlr[j] = 1.0f / __shfl(l_col, lgrp * 4 + j, 64);
#pragma unroll
  for (int nf = 0; nf < 4; ++nf)
#pragma unroll
    for (int j = 0; j < 4; ++j) {
      int row = r0 + lgrp * 4 + j;
      attn_buf[(size_t)row * (NH * HD) + h * HD + nf * 16 + lrow] =
          (__bf16)(oacc[nf][j] * rlr[j]);
    }
}

extern "C" void kernel_launch(void* const* d_in, const int* in_sizes, int n_in,
                              void* d_out, int out_size, void* d_ws, size_t ws_size,
                              hipStream_t stream)
{
  const float* x  = (const float*)d_in[0];
  const float* wq = (const float*)d_in[1];
  const float* wk = (const float*)d_in[2];
  const float* wv = (const float*)d_in[3];
  const float* wo = (const float*)d_in[4];
  const float* fc = (const float*)d_in[5];
  float* out = (float*)d_out;

  char* ws = (char*)d_ws;
  __bf16* q_buf    = (__bf16*)(ws);                       //  8 MB [NH][S][HD]
  __bf16* k_buf    = (__bf16*)(ws +  8u * 1024 * 1024);   //  2 MB [NKV][S][HD]
  __bf16* v_buf    = (__bf16*)(ws + 10u * 1024 * 1024);   //  2 MB [NKV][HD][S]
  __bf16* attn_buf = (__bf16*)(ws + 12u * 1024 * 1024);   //  8 MB [S][NH*HD]
  __bf16* xb       = (__bf16*)(ws + 20u * 1024 * 1024);   //  8 MB [S][DIM]
  __bf16* wb       = (__bf16*)(ws + 28u * 1024 * 1024);   // 12 MB [3072][DIM]

  cvt_xw<<<dim3(10240), 256, 0, stream>>>(x, wq, wk, wv, xb, wb);
  qkv_gemm<<<dim3(384), 512, 0, stream>>>(xb, wb, q_buf, k_buf, v_buf);
  rope_k<<<dim3(2048), 256, 0, stream>>>(k_buf, fc);
  attn_kernel<<<dim3(16, 32), 512, 0, stream>>>(q_buf, k_buf, v_buf, fc, attn_buf);
  oproj_gemm<<<dim3(256), 512, 0, stream>>>(attn_buf, wo, out);
}

// Round 8
// 156.147 us; speedup vs baseline: 1.2604x; 1.1086x over previous
//
#include <hip/hip_runtime.h>
#include <hip/hip_bf16.h>

#define S_LEN 2048
#define DIM_  2048
#define NH    32
#define NKV   8
#define HD    64

typedef __bf16 bf16x8 __attribute__((ext_vector_type(8)));
typedef __bf16 bf16x4 __attribute__((ext_vector_type(4)));
typedef float  f32x4  __attribute__((ext_vector_type(4)));

#define AS_GLOBAL(p) ((const __attribute__((address_space(1))) void*)(p))
#define AS_LDS(p)    ((__attribute__((address_space(3))) void*)(p))

__device__ __forceinline__ bf16x8 pack8(float4 a, float4 b) {
  bf16x8 r;
  r[0] = (__bf16)a.x; r[1] = (__bf16)a.y; r[2] = (__bf16)a.z; r[3] = (__bf16)a.w;
  r[4] = (__bf16)b.x; r[5] = (__bf16)b.y; r[6] = (__bf16)b.z; r[7] = (__bf16)b.w;
  return r;
}

// ---------------- fp32 -> bf16 conversion (x, wq|wk|wv concat) --------------
__global__ __launch_bounds__(256) void cvt_xw(
    const float* __restrict__ x,  const float* __restrict__ wq,
    const float* __restrict__ wk, const float* __restrict__ wv,
    __bf16* __restrict__ xb, __bf16* __restrict__ wb)
{
  size_t i = (size_t)blockIdx.x * 256 + threadIdx.x;
  const float* src; __bf16* dst; size_t off;
  if (i < 1048576)      { src = x;  dst = xb;            off = i; }
  else if (i < 2097152) { src = wq; dst = wb;            off = i - 1048576; }
  else if (i < 2359296) { src = wk; dst = wb + 4194304;  off = i - 2097152; }
  else                  { src = wv; dst = wb + 5242880;  off = i - 2359296; }
  float4 f = ((const float4*)src)[off];
  bf16x4 r;
  r[0] = (__bf16)f.x; r[1] = (__bf16)f.y; r[2] = (__bf16)f.z; r[3] = (__bf16)f.w;
  ((bf16x4*)dst)[off] = r;
}

// ---------------- QKV projection: 64x128 tiles, 768 blocks (3/CU) ----------
#define BK 32

// 512 threads stage one 128x32 bf16 tile (8 KB): one 16B chunk each.
__device__ __forceinline__ void stage_tileB(
    const __bf16* __restrict__ g, int row0, int k0, int ld, __bf16* lds)
{
  const int tid = threadIdx.x;
  int off = tid * 16;
  int r = off >> 6;          // 64 B per row (32 bf16)
  int c = (off & 63) >> 1;
  __builtin_amdgcn_global_load_lds(
      AS_GLOBAL(g + (size_t)(row0 + r) * ld + k0 + c),
      AS_LDS(lds + (tid >> 6) * 512), 16, 0, 0);
}

// threads 0..255 stage one 64x32 bf16 tile (4 KB).
__device__ __forceinline__ void stage_tileA(
    const __bf16* __restrict__ g, int row0, int k0, int ld, __bf16* lds)
{
  const int tid = threadIdx.x;
  if (tid < 256) {
    int off = tid * 16;
    int r = off >> 6;
    int c = (off & 63) >> 1;
    __builtin_amdgcn_global_load_lds(
        AS_GLOBAL(g + (size_t)(row0 + r) * ld + k0 + c),
        AS_LDS(lds + (tid >> 6) * 512), 16, 0, 0);
  }
}

__global__ __launch_bounds__(512) void qkv_gemm(
    const __bf16* __restrict__ xb, const __bf16* __restrict__ wb,
    __bf16* __restrict__ q_buf, __bf16* __restrict__ k_buf, __bf16* __restrict__ v_buf)
{
  __shared__ __bf16 As[2 * 2048];   // 64x32 dbuf
  __shared__ __bf16 Bs[2 * 4096];   // 128x32 dbuf
  const int lane = threadIdx.x & 63;
  const int wave = threadIdx.x >> 6;
  const int wr = wave >> 2, wc = wave & 3;   // 2x4 wave grid -> wave 32x32
  const int fr = lane & 15, fg = lane >> 4;

  // XCD swizzle: per XCD, 3 col-panels x 32 row-tiles (B L2-resident)
  const int lid = blockIdx.x;        // 0..767
  const int xcd = lid & 7;
  const int i   = lid >> 3;          // 0..95
  const int row0 = (i & 31) * 64;
  const int col0 = (xcd * 3 + (i >> 5)) * 128;

  f32x4 acc[2][2] = {};
  const int nt = DIM_ / BK;

  stage_tileA(xb, row0, 0, DIM_, As);
  stage_tileB(wb, col0, 0, DIM_, Bs);

  for (int t = 0; t < nt; ++t) {
    const int cur = t & 1;
    if (t + 1 < nt) {
      stage_tileA(xb, row0, (t + 1) * BK, DIM_, As + (cur ^ 1) * 2048);
      stage_tileB(wb, col0, (t + 1) * BK, DIM_, Bs + (cur ^ 1) * 4096);
    }
    __syncthreads();
    bf16x8 a[2], b[2];
#pragma unroll
    for (int mi = 0; mi < 2; ++mi)
      a[mi] = *(const bf16x8*)(As + cur * 2048 + (wr * 32 + mi * 16 + fr) * 32 + fg * 8);
#pragma unroll
    for (int ni = 0; ni < 2; ++ni)
      b[ni] = *(const bf16x8*)(Bs + cur * 4096 + (wc * 32 + ni * 16 + fr) * 32 + fg * 8);
#pragma unroll
    for (int mi = 0; mi < 2; ++mi)
#pragma unroll
      for (int ni = 0; ni < 2; ++ni)
        acc[mi][ni] = __builtin_amdgcn_mfma_f32_16x16x32_bf16(a[mi], b[ni], acc[mi][ni], 0, 0, 0);
    __syncthreads();
  }

  const int rowg0 = row0 + wr * 32;
  const int colg0 = col0 + wc * 32;
#pragma unroll
  for (int mi = 0; mi < 2; ++mi) {
#pragma unroll
    for (int ni = 0; ni < 2; ++ni) {
#pragma unroll
      for (int j = 0; j < 4; ++j) {
        int row = rowg0 + mi * 16 + fg * 4 + j;
        int col = colg0 + ni * 16 + fr;
        float v = acc[mi][ni][j];
        if (col < 2048) {
          int h = col >> 6, d = col & 63;
          q_buf[((size_t)h * S_LEN + row) * HD + d] = (__bf16)v;
        } else if (col < 2560) {
          int c = col - 2048, g = c >> 6, d = c & 63;
          k_buf[((size_t)g * S_LEN + row) * HD + d] = (__bf16)v;
        } else {
          int c = col - 2560, g = c >> 6, d = c & 63;
          v_buf[((size_t)g * HD + d) * S_LEN + row] = (__bf16)v;  // transposed
        }
      }
    }
  }
}

// ---------------- Output projection: attn(bf16) @ wo(fp32)^T -> fp32 --------
#define BK64   64
#define TILE64 8192   // 128*64 bf16

__global__ __launch_bounds__(512) void oproj_gemm(
    const __bf16* __restrict__ attn_buf, const float* __restrict__ wo,
    float* __restrict__ out)
{
  __shared__ __bf16 As[2 * TILE64];
  __shared__ __bf16 Bs[2 * TILE64];
  const int tid  = threadIdx.x;
  const int lane = tid & 63;
  const int wave = tid >> 6;
  const int wr = wave >> 2, wc = wave & 3;
  const int fr = lane & 15, fg = lane >> 4;

  int lid = blockIdx.x;
  int swz = (lid & 7) * 32 + (lid >> 3);
  const int row0 = (swz >> 4) * 128;
  const int col0 = (swz & 15) * 128;

  const int srow = tid >> 2;
  const int sc4  = tid & 3;
  const int wch0 = (2 * sc4)     ^ (srow & 7);
  const int wch1 = (2 * sc4 + 1) ^ (srow & 7);
  const int nt = DIM_ / BK64;

  bf16x8 ar[2], br[2];
  auto loadAB = [&](int t) {
    const int k0 = t * BK64;
    const __bf16* p = attn_buf + (size_t)(row0 + srow) * DIM_ + k0 + sc4 * 16;
    ar[0] = *(const bf16x8*)(p);
    ar[1] = *(const bf16x8*)(p + 8);
    const float* q = wo + (size_t)(col0 + srow) * DIM_ + k0 + sc4 * 16;
    float4 g0 = ((const float4*)q)[0], g1 = ((const float4*)q)[1];
    float4 g2 = ((const float4*)q)[2], g3 = ((const float4*)q)[3];
    br[0] = pack8(g0, g1); br[1] = pack8(g2, g3);
  };
  auto writeAB = [&](int buf) {
    __bf16* a = As + buf * TILE64 + srow * 64;
    __bf16* b = Bs + buf * TILE64 + srow * 64;
    *(bf16x8*)(a + wch0 * 8) = ar[0];
    *(bf16x8*)(a + wch1 * 8) = ar[1];
    *(bf16x8*)(b + wch0 * 8) = br[0];
    *(bf16x8*)(b + wch1 * 8) = br[1];
  };

  f32x4 acc[4][2] = {};
  loadAB(0);
  writeAB(0);
  __syncthreads();

  for (int t = 0; t < nt; ++t) {
    const int cur = t & 1;
    loadAB(t + 1 < nt ? t + 1 : t);
#pragma unroll
    for (int kk = 0; kk < 2; ++kk) {
      bf16x8 a[4], b[2];
#pragma unroll
      for (int mi = 0; mi < 4; ++mi) {
        int R = wr * 64 + mi * 16 + fr;
        a[mi] = *(const bf16x8*)(As + cur * TILE64 + R * 64 + (((kk * 4 + fg) ^ (fr & 7)) * 8));
      }
#pragma unroll
      for (int ni = 0; ni < 2; ++ni) {
        int R = wc * 32 + ni * 16 + fr;
        b[ni] = *(const bf16x8*)(Bs + cur * TILE64 + R * 64 + (((kk * 4 + fg) ^ (fr & 7)) * 8));
      }
#pragma unroll
      for (int mi = 0; mi < 4; ++mi)
#pragma unroll
        for (int ni = 0; ni < 2; ++ni)
          acc[mi][ni] = __builtin_amdgcn_mfma_f32_16x16x32_bf16(a[mi], b[ni], acc[mi][ni], 0, 0, 0);
    }
    writeAB(cur ^ 1);
    __syncthreads();
  }

  const int rowg0 = row0 + wr * 64;
  const int colg0 = col0 + wc * 32;
#pragma unroll
  for (int mi = 0; mi < 4; ++mi)
#pragma unroll
    for (int ni = 0; ni < 2; ++ni)
#pragma unroll
      for (int j = 0; j < 4; ++j) {
        int row = rowg0 + mi * 16 + fg * 4 + j;
        int col = colg0 + ni * 16 + fr;
        out[(size_t)row * DIM_ + col] = acc[mi][ni][j];
      }
}

// ---------------- RoPE on K only (in place, bf16); Q fused into attn --------
__global__ __launch_bounds__(256) void rope_k(
    __bf16* __restrict__ k_buf, const float* __restrict__ fc)
{
  int idx = blockIdx.x * 256 + threadIdx.x;
  int i    = idx & 31;
  int sp   = (idx >> 5) & (S_LEN - 1);
  int g    = idx >> 16;
  __bf16* buf = k_buf + ((size_t)g * S_LEN + sp) * HD;
  float c = fc[(sp * 32 + i) * 2 + 0];
  float s = fc[(sp * 32 + i) * 2 + 1];
  float x1 = (float)buf[2 * i], x2 = (float)buf[2 * i + 1];
  buf[2 * i + 0] = (__bf16)(x1 * c - x2 * s);
  buf[2 * i + 1] = (__bf16)(x1 * s + x2 * c);
}

// ---------------- Flash attention (causal, GQA, swapped-QK, shared KV) ------
// 1-D grid 512, PAIRED dispatch: blocks 0..255 = long q-tiles (qt=15..8),
// blocks 256..511 = short (qt=0..7). Co-resident pair on a CU sums to a
// constant 36 tile-iterations -> balanced, ~16 active waves/CU throughout.
__global__ __launch_bounds__(512) void attn_kernel(
    const __bf16* __restrict__ q_buf, const __bf16* __restrict__ k_buf,
    const __bf16* __restrict__ v_buf, const float* __restrict__ fc,
    __bf16* __restrict__ attn_buf)
{
  __shared__ __align__(16) __bf16 Ks[2][64 * 64];   // 2 x 8 KB
  __shared__ __align__(16) __bf16 Vs[2][64 * 64];   // 2 x 8 KB (V^T: [d][kv])
  __shared__ __align__(16) __bf16 lds_p[8][16][72]; // per-wave P slab

  const int tid  = threadIdx.x;
  const int lane = tid & 63;
  const int wave = tid >> 6;
  const int n = blockIdx.x;
  const int qt = (n < 256) ? (15 - (n >> 5)) : ((n - 256) >> 5);
  const int h  = n & 31;
  const int g = h >> 2;             // NREP = 4
  const int r0 = qt * 128 + wave * 16;
  const int lrow = lane & 15;
  const int lgrp = lane >> 4;
  const int lk = lgrp * 8;

  const __bf16* qh = q_buf + (size_t)h * S_LEN * HD;
  const __bf16* kh = k_buf + (size_t)g * S_LEN * HD;
  const __bf16* vh = v_buf + (size_t)g * HD * S_LEN;

  const int sr   = tid >> 3;            // staging row 0..63
  const int scol = tid & 7;             // source 16B chunk
  const int dcol = scol ^ (sr & 7);     // swizzled dest chunk

  // ---- load Q fragment + apply RoPE in-register ----
  bf16x8 qa[2];
  const float* fcrow = fc + (size_t)(r0 + lrow) * 64;
#pragma unroll
  for (int kk = 0; kk < 2; ++kk) {
    qa[kk] = *(const bf16x8*)(qh + (size_t)(r0 + lrow) * HD + kk * 32 + lk);
    float4 cs0 = *(const float4*)(fcrow + (kk * 16 + lgrp * 4) * 2);
    float4 cs1 = *(const float4*)(fcrow + (kk * 16 + lgrp * 4) * 2 + 4);
    float cc[4] = {cs0.x, cs0.z, cs1.x, cs1.z};
    float ss[4] = {cs0.y, cs0.w, cs1.y, cs1.w};
#pragma unroll
    for (int pr = 0; pr < 4; ++pr) {
      float x1 = (float)qa[kk][2 * pr], x2 = (float)qa[kk][2 * pr + 1];
      qa[kk][2 * pr]     = (__bf16)(x1 * cc[pr] - x2 * ss[pr]);
      qa[kk][2 * pr + 1] = (__bf16)(x1 * ss[pr] + x2 * cc[pr]);
    }
  }

  const float KS = 0.125f * 1.44269504088896f;  // scale * log2(e)
  float m_col = -3.0e38f, l_col = 0.f;
  f32x4 oacc[4] = {};

  const int nt = 2 * qt + 2;

  {
    uint4 k0 = *(const uint4*)(kh + (size_t)sr * HD + scol * 8);
    uint4 v0 = *(const uint4*)(vh + (size_t)sr * S_LEN + scol * 8);
    *(uint4*)(&Ks[0][sr * 64 + dcol * 8]) = k0;
    *(uint4*)(&Vs[0][sr * 64 + dcol * 8]) = v0;
  }
  __syncthreads();

  for (int t = 0; t < nt; ++t) {
    const int cur = t & 1;
    const int t0 = t * 64;

    const int tn0 = (t + 1 < nt ? t + 1 : t) * 64;
    uint4 kreg = *(const uint4*)(kh + (size_t)(tn0 + sr) * HD + scol * 8);
    uint4 vreg = *(const uint4*)(vh + (size_t)sr * S_LEN + tn0 + scol * 8);

    const int dmax = r0 + 15 - t0;
    if (dmax >= 0) {
      f32x4 sc[4] = {};
      const int cmax = dmax >> 4;
      __builtin_amdgcn_s_setprio(1);
#pragma unroll
      for (int c = 0; c < 4; ++c) {
        if (c <= cmax) {
#pragma unroll
          for (int kk = 0; kk < 2; ++kk) {
            bf16x8 ka = *(const bf16x8*)(
                &Ks[cur][(c * 16 + lrow) * 64 + (((kk * 4 + lgrp) ^ (lrow & 7)) * 8)]);
            sc[c] = __builtin_amdgcn_mfma_f32_16x16x32_bf16(ka, qa[kk], sc[c], 0, 0, 0);
          }
        }
      }
      __builtin_amdgcn_s_setprio(0);

      float p[16];
      const int q = r0 + lrow;
      if (t0 + 63 <= r0) {
#pragma unroll
        for (int c = 0; c < 4; ++c)
#pragma unroll
          for (int j = 0; j < 4; ++j)
            p[c * 4 + j] = sc[c][j] * KS;
      } else {
#pragma unroll
        for (int c = 0; c < 4; ++c)
#pragma unroll
          for (int j = 0; j < 4; ++j) {
            int kv = t0 + c * 16 + lgrp * 4 + j;
            p[c * 4 + j] = (kv <= q) ? sc[c][j] * KS : -3.0e38f;
          }
      }

      float m8[8], m4[4];
#pragma unroll
      for (int i = 0; i < 8; ++i) m8[i] = fmaxf(p[i], p[i + 8]);
#pragma unroll
      for (int i = 0; i < 4; ++i) m4[i] = fmaxf(m8[i], m8[i + 4]);
      float mx = fmaxf(fmaxf(m4[0], m4[1]), fmaxf(m4[2], m4[3]));
      mx = fmaxf(mx, __shfl_xor(mx, 16, 64));
      mx = fmaxf(mx, __shfl_xor(mx, 32, 64));

      if (__all(mx <= m_col + 8.f)) {
        // defer: alpha == 1
      } else {
        float nm = fmaxf(m_col, mx);
        float alpha = __builtin_amdgcn_exp2f(m_col - nm);
        m_col = nm;
        float ar[4];
#pragma unroll
        for (int j = 0; j < 4; ++j)
          ar[j] = __shfl(alpha, lgrp * 4 + j, 64);
#pragma unroll
        for (int nf = 0; nf < 4; ++nf)
#pragma unroll
          for (int j = 0; j < 4; ++j)
            oacc[nf][j] *= ar[j];
        l_col *= alpha;
      }

#pragma unroll
      for (int i = 0; i < 16; ++i)
        p[i] = __builtin_amdgcn_exp2f(p[i] - m_col);
      float s8[8], s4[4];
#pragma unroll
      for (int i = 0; i < 8; ++i) s8[i] = p[i] + p[i + 8];
#pragma unroll
      for (int i = 0; i < 4; ++i) s4[i] = s8[i] + s8[i + 4];
      float rs = (s4[0] + s4[1]) + (s4[2] + s4[3]);
      rs += __shfl_xor(rs, 16, 64);
      rs += __shfl_xor(rs, 32, 64);
      l_col += rs;

#pragma unroll
      for (int c = 0; c < 4; ++c)
#pragma unroll
        for (int e = 0; e < 2; ++e) {
          union { __bf16 hh[2]; unsigned u; } pk;
          pk.hh[0] = (__bf16)p[c * 4 + 2 * e];
          pk.hh[1] = (__bf16)p[c * 4 + 2 * e + 1];
          *(unsigned*)&lds_p[wave][lrow][c * 16 + lgrp * 4 + 2 * e] = pk.u;
        }
      asm volatile("s_waitcnt lgkmcnt(0)" ::: "memory");

      bf16x8 pa0 = *(const bf16x8*)&lds_p[wave][lrow][lk];
      __builtin_amdgcn_s_setprio(1);
#pragma unroll
      for (int nf = 0; nf < 4; ++nf) {
        bf16x8 vb = *(const bf16x8*)(
            &Vs[cur][(nf * 16 + lrow) * 64 + ((lgrp ^ (lrow & 7)) * 8)]);
        oacc[nf] = __builtin_amdgcn_mfma_f32_16x16x32_bf16(pa0, vb, oacc[nf], 0, 0, 0);
      }
      __builtin_amdgcn_s_setprio(0);
      if (dmax >= 32) {
        bf16x8 pa1 = *(const bf16x8*)&lds_p[wave][lrow][32 + lk];
        __builtin_amdgcn_s_setprio(1);
#pragma unroll
        for (int nf = 0; nf < 4; ++nf) {
          bf16x8 vb = *(const bf16x8*)(
              &Vs[cur][(nf * 16 + lrow) * 64 + (((4 + lgrp) ^ (lrow & 7)) * 8)]);
          oacc[nf] = __builtin_amdgcn_mfma_f32_16x16x32_bf16(pa1, vb, oacc[nf], 0, 0, 0);
        }
        __builtin_amdgcn_s_setprio(0);
      }
    }

    *(uint4*)(&Ks[cur ^ 1][sr * 64 + dcol * 8]) = kreg;
    *(uint4*)(&Vs[cur ^ 1][sr * 64 + dcol * 8]) = vreg;
    __syncthreads();
  }

  float rlr[4];
#pragma unroll
  for (int j = 0; j < 4; ++j)
    rlr[j] = 1.0f / __shfl(l_col, lgrp * 4 + j, 64);
#pragma unroll
  for (int nf = 0; nf < 4; ++nf)
#pragma unroll
    for (int j = 0; j < 4; ++j) {
      int row = r0 + lgrp * 4 + j;
      attn_buf[(size_t)row * (NH * HD) + h * HD + nf * 16 + lrow] =
          (__bf16)(oacc[nf][j] * rlr[j]);
    }
}

extern "C" void kernel_launch(void* const* d_in, const int* in_sizes, int n_in,
                              void* d_out, int out_size, void* d_ws, size_t ws_size,
                              hipStream_t stream)
{
  const float* x  = (const float*)d_in[0];
  const float* wq = (const float*)d_in[1];
  const float* wk = (const float*)d_in[2];
  const float* wv = (const float*)d_in[3];
  const float* wo = (const float*)d_in[4];
  const float* fc = (const float*)d_in[5];
  float* out = (float*)d_out;

  char* ws = (char*)d_ws;
  __bf16* q_buf    = (__bf16*)(ws);                       //  8 MB [NH][S][HD]
  __bf16* k_buf    = (__bf16*)(ws +  8u * 1024 * 1024);   //  2 MB [NKV][S][HD]
  __bf16* v_buf    = (__bf16*)(ws + 10u * 1024 * 1024);   //  2 MB [NKV][HD][S]
  __bf16* attn_buf = (__bf16*)(ws + 12u * 1024 * 1024);   //  8 MB [S][NH*HD]
  __bf16* xb       = (__bf16*)(ws + 20u * 1024 * 1024);   //  8 MB [S][DIM]
  __bf16* wb       = (__bf16*)(ws + 28u * 1024 * 1024);   // 12 MB [3072][DIM]

  cvt_xw<<<dim3(10240), 256, 0, stream>>>(x, wq, wk, wv, xb, wb);
  qkv_gemm<<<dim3(768), 512, 0, stream>>>(xb, wb, q_buf, k_buf, v_buf);
  rope_k<<<dim3(2048), 256, 0, stream>>>(k_buf, fc);
  attn_kernel<<<dim3(512), 512, 0, stream>>>(q_buf, k_buf, v_buf, fc, attn_buf);
  oproj_gemm<<<dim3(256), 512, 0, stream>>>(attn_buf, wo, out);
}

// Round 9
// 156.135 us; speedup vs baseline: 1.2605x; 1.0001x over previous
//
#include <hip/hip_runtime.h>
#include <hip/hip_bf16.h>

#define S_LEN 2048
#define DIM_  2048
#define NH    32
#define NKV   8
#define HD    64

typedef __bf16 bf16x8 __attribute__((ext_vector_type(8)));
typedef __bf16 bf16x4 __attribute__((ext_vector_type(4)));
typedef float  f32x4  __attribute__((ext_vector_type(4)));

#define AS_GLOBAL(p) ((const __attribute__((address_space(1))) void*)(p))
#define AS_LDS(p)    ((__attribute__((address_space(3))) void*)(p))

// ---------------- fp32 -> bf16 conversion (x, wq|wk|wv concat, wo) ----------
// Grid 14336 x 256: one float4 per thread.
__global__ __launch_bounds__(256) void cvt_xw(
    const float* __restrict__ x,  const float* __restrict__ wq,
    const float* __restrict__ wk, const float* __restrict__ wv,
    const float* __restrict__ wo,
    __bf16* __restrict__ xb, __bf16* __restrict__ wb, __bf16* __restrict__ wob)
{
  size_t i = (size_t)blockIdx.x * 256 + threadIdx.x;
  const float* src; __bf16* dst; size_t off;
  if (i < 1048576)      { src = x;  dst = xb;            off = i; }
  else if (i < 2097152) { src = wq; dst = wb;            off = i - 1048576; }
  else if (i < 2359296) { src = wk; dst = wb + 4194304;  off = i - 2097152; }
  else if (i < 2621440) { src = wv; dst = wb + 5242880;  off = i - 2359296; }
  else                  { src = wo; dst = wob;           off = i - 2621440; }
  float4 f = ((const float4*)src)[off];
  bf16x4 r;
  r[0] = (__bf16)f.x; r[1] = (__bf16)f.y; r[2] = (__bf16)f.z; r[3] = (__bf16)f.w;
  ((bf16x4*)dst)[off] = r;
}

// ---------------- 128x128 bf16 GEMM, BK=32, 8 waves, global_load_lds --------
#define BK 32
#define TILE_ELEMS 4096   // 128*32

// 512 threads stage one 128x32 bf16 tile (8 KB): one 16B chunk each.
__device__ __forceinline__ void stage_tile(
    const __bf16* __restrict__ g, int row0, int k0, int ld, __bf16* lds)
{
  const int tid = threadIdx.x;
  int off = tid * 16;        // byte offset in 8 KB tile
  int r = off >> 6;          // 64 B per row (32 bf16)
  int c = (off & 63) >> 1;   // bf16 col
  __builtin_amdgcn_global_load_lds(
      AS_GLOBAL(g + (size_t)(row0 + r) * ld + k0 + c),
      AS_LDS(lds + (tid >> 6) * 512),   // wave-uniform base + lane*16
      16, 0, 0);
}

__device__ __forceinline__ void gemm_mainloop(
    const __bf16* __restrict__ A, const __bf16* __restrict__ B,
    int row0, int col0, int lda, int ldb, int nt,
    __bf16* As, __bf16* Bs, f32x4 acc[4][2])
{
  const int lane = threadIdx.x & 63;
  const int wave = threadIdx.x >> 6;
  const int wr = wave >> 2, wc = wave & 3;   // 2x4 wave grid
  const int fr = lane & 15, fg = lane >> 4;

  stage_tile(A, row0, 0, lda, As);
  stage_tile(B, col0, 0, ldb, Bs);

  for (int t = 0; t < nt; ++t) {
    const int cur = t & 1;
    if (t + 1 < nt) {
      stage_tile(A, row0, (t + 1) * BK, lda, As + (cur ^ 1) * TILE_ELEMS);
      stage_tile(B, col0, (t + 1) * BK, ldb, Bs + (cur ^ 1) * TILE_ELEMS);
    }
    __syncthreads();
    bf16x8 a[4], b[2];
#pragma unroll
    for (int mi = 0; mi < 4; ++mi)
      a[mi] = *(const bf16x8*)(As + cur * TILE_ELEMS + (wr * 64 + mi * 16 + fr) * 32 + fg * 8);
#pragma unroll
    for (int ni = 0; ni < 2; ++ni)
      b[ni] = *(const bf16x8*)(Bs + cur * TILE_ELEMS + (wc * 32 + ni * 16 + fr) * 32 + fg * 8);
#pragma unroll
    for (int mi = 0; mi < 4; ++mi)
#pragma unroll
      for (int ni = 0; ni < 2; ++ni)
        acc[mi][ni] = __builtin_amdgcn_mfma_f32_16x16x32_bf16(a[mi], b[ni], acc[mi][ni], 0, 0, 0);
    __syncthreads();
  }
}

// ---------------- QKV projection (bf16 inputs, 384 blocks, XCD swizzle) -----
__global__ __launch_bounds__(512) void qkv_gemm(
    const __bf16* __restrict__ xb, const __bf16* __restrict__ wb,
    __bf16* __restrict__ q_buf, __bf16* __restrict__ k_buf, __bf16* __restrict__ v_buf)
{
  __shared__ __bf16 As[2 * TILE_ELEMS];
  __shared__ __bf16 Bs[2 * TILE_ELEMS];
  const int lane = threadIdx.x & 63;
  const int wave = threadIdx.x >> 6;
  const int wr = wave >> 2, wc = wave & 3;
  const int fr = lane & 15, fg = lane >> 4;

  // XCD swizzle: contiguous 48-block chunks (2 row-panels) per XCD
  int lid = blockIdx.x;                    // 0..383
  int swz = (lid & 7) * 48 + (lid >> 3);
  const int row0 = (swz / 24) * 128;
  const int col0 = (swz % 24) * 128;

  f32x4 acc[4][2] = {};
  gemm_mainloop(xb, wb, row0, col0, DIM_, DIM_, DIM_ / BK, As, Bs, acc);

  const int rowg0 = row0 + wr * 64;
  const int colg0 = col0 + wc * 32;
#pragma unroll
  for (int mi = 0; mi < 4; ++mi) {
#pragma unroll
    for (int ni = 0; ni < 2; ++ni) {
#pragma unroll
      for (int j = 0; j < 4; ++j) {
        int row = rowg0 + mi * 16 + fg * 4 + j;
        int col = colg0 + ni * 16 + fr;
        float v = acc[mi][ni][j];
        if (col < 2048) {
          int h = col >> 6, d = col & 63;
          q_buf[((size_t)h * S_LEN + row) * HD + d] = (__bf16)v;
        } else if (col < 2560) {
          int c = col - 2048, g = c >> 6, d = c & 63;
          k_buf[((size_t)g * S_LEN + row) * HD + d] = (__bf16)v;
        } else {
          int c = col - 2560, g = c >> 6, d = c & 63;
          v_buf[((size_t)g * HD + d) * S_LEN + row] = (__bf16)v;  // transposed
        }
      }
    }
  }
}

// ---------------- Output projection: attn(bf16) @ wob(bf16)^T -> fp32 -------
__global__ __launch_bounds__(512) void oproj_gemm(
    const __bf16* __restrict__ attn_buf, const __bf16* __restrict__ wob,
    float* __restrict__ out)
{
  __shared__ __bf16 As[2 * TILE_ELEMS];
  __shared__ __bf16 Bs[2 * TILE_ELEMS];
  const int lane = threadIdx.x & 63;
  const int wave = threadIdx.x >> 6;
  const int wr = wave >> 2, wc = wave & 3;
  const int fr = lane & 15, fg = lane >> 4;

  // XCD swizzle: 32-block chunks (2 row-panels x 16 cols) per XCD
  int lid = blockIdx.x;                    // 0..255
  int swz = (lid & 7) * 32 + (lid >> 3);
  const int row0 = (swz >> 4) * 128;
  const int col0 = (swz & 15) * 128;

  f32x4 acc[4][2] = {};
  gemm_mainloop(attn_buf, wob, row0, col0, DIM_, DIM_, DIM_ / BK, As, Bs, acc);

  const int rowg0 = row0 + wr * 64;
  const int colg0 = col0 + wc * 32;
#pragma unroll
  for (int mi = 0; mi < 4; ++mi)
#pragma unroll
    for (int ni = 0; ni < 2; ++ni)
#pragma unroll
      for (int j = 0; j < 4; ++j) {
        int row = rowg0 + mi * 16 + fg * 4 + j;
        int col = colg0 + ni * 16 + fr;
        out[(size_t)row * DIM_ + col] = acc[mi][ni][j];
      }
}

// ---------------- RoPE on K only (in place, bf16); Q fused into attn --------
__global__ __launch_bounds__(256) void rope_k(
    __bf16* __restrict__ k_buf, const float* __restrict__ fc)
{
  int idx = blockIdx.x * 256 + threadIdx.x;
  int i    = idx & 31;
  int sp   = (idx >> 5) & (S_LEN - 1);
  int g    = idx >> 16;
  __bf16* buf = k_buf + ((size_t)g * S_LEN + sp) * HD;
  float c = fc[(sp * 32 + i) * 2 + 0];
  float s = fc[(sp * 32 + i) * 2 + 1];
  float x1 = (float)buf[2 * i], x2 = (float)buf[2 * i + 1];
  buf[2 * i + 0] = (__bf16)(x1 * c - x2 * s);
  buf[2 * i + 1] = (__bf16)(x1 * s + x2 * c);
}

// ---------------- Flash attention (causal, GQA, swapped-QK, shared KV) ------
// 1-D grid 512, PAIRED dispatch: blocks 0..255 = long q-tiles, 256..511 short.
__global__ __launch_bounds__(512) void attn_kernel(
    const __bf16* __restrict__ q_buf, const __bf16* __restrict__ k_buf,
    const __bf16* __restrict__ v_buf, const float* __restrict__ fc,
    __bf16* __restrict__ attn_buf)
{
  __shared__ __align__(16) __bf16 Ks[2][64 * 64];   // 2 x 8 KB
  __shared__ __align__(16) __bf16 Vs[2][64 * 64];   // 2 x 8 KB (V^T: [d][kv])
  __shared__ __align__(16) __bf16 lds_p[8][16][72]; // per-wave P slab

  const int tid  = threadIdx.x;
  const int lane = tid & 63;
  const int wave = tid >> 6;
  const int n = blockIdx.x;
  const int qt = (n < 256) ? (15 - (n >> 5)) : ((n - 256) >> 5);
  const int h  = n & 31;
  const int g = h >> 2;             // NREP = 4
  const int r0 = qt * 128 + wave * 16;
  const int lrow = lane & 15;
  const int lgrp = lane >> 4;
  const int lk = lgrp * 8;

  const __bf16* qh = q_buf + (size_t)h * S_LEN * HD;
  const __bf16* kh = k_buf + (size_t)g * S_LEN * HD;
  const __bf16* vh = v_buf + (size_t)g * HD * S_LEN;

  const int sr   = tid >> 3;            // staging row 0..63
  const int scol = tid & 7;             // source 16B chunk
  const int dcol = scol ^ (sr & 7);     // swizzled dest chunk

  // ---- load Q fragment + apply RoPE in-register ----
  bf16x8 qa[2];
  const float* fcrow = fc + (size_t)(r0 + lrow) * 64;
#pragma unroll
  for (int kk = 0; kk < 2; ++kk) {
    qa[kk] = *(const bf16x8*)(qh + (size_t)(r0 + lrow) * HD + kk * 32 + lk);
    float4 cs0 = *(const float4*)(fcrow + (kk * 16 + lgrp * 4) * 2);
    float4 cs1 = *(const float4*)(fcrow + (kk * 16 + lgrp * 4) * 2 + 4);
    float cc[4] = {cs0.x, cs0.z, cs1.x, cs1.z};
    float ss[4] = {cs0.y, cs0.w, cs1.y, cs1.w};
#pragma unroll
    for (int pr = 0; pr < 4; ++pr) {
      float x1 = (float)qa[kk][2 * pr], x2 = (float)qa[kk][2 * pr + 1];
      qa[kk][2 * pr]     = (__bf16)(x1 * cc[pr] - x2 * ss[pr]);
      qa[kk][2 * pr + 1] = (__bf16)(x1 * ss[pr] + x2 * cc[pr]);
    }
  }

  const float KS = 0.125f * 1.44269504088896f;  // scale * log2(e)
  float m_col = -3.0e38f, l_col = 0.f;
  f32x4 oacc[4] = {};

  const int nt = 2 * qt + 2;

  {
    uint4 k0 = *(const uint4*)(kh + (size_t)sr * HD + scol * 8);
    uint4 v0 = *(const uint4*)(vh + (size_t)sr * S_LEN + scol * 8);
    *(uint4*)(&Ks[0][sr * 64 + dcol * 8]) = k0;
    *(uint4*)(&Vs[0][sr * 64 + dcol * 8]) = v0;
  }
  __syncthreads();

  for (int t = 0; t < nt; ++t) {
    const int cur = t & 1;
    const int t0 = t * 64;

    const int tn0 = (t + 1 < nt ? t + 1 : t) * 64;
    uint4 kreg = *(const uint4*)(kh + (size_t)(tn0 + sr) * HD + scol * 8);
    uint4 vreg = *(const uint4*)(vh + (size_t)sr * S_LEN + tn0 + scol * 8);

    const int dmax = r0 + 15 - t0;
    if (dmax >= 0) {
      f32x4 sc[4] = {};
      const int cmax = dmax >> 4;
      __builtin_amdgcn_s_setprio(1);
#pragma unroll
      for (int c = 0; c < 4; ++c) {
        if (c <= cmax) {
#pragma unroll
          for (int kk = 0; kk < 2; ++kk) {
            bf16x8 ka = *(const bf16x8*)(
                &Ks[cur][(c * 16 + lrow) * 64 + (((kk * 4 + lgrp) ^ (lrow & 7)) * 8)]);
            sc[c] = __builtin_amdgcn_mfma_f32_16x16x32_bf16(ka, qa[kk], sc[c], 0, 0, 0);
          }
        }
      }
      __builtin_amdgcn_s_setprio(0);

      float p[16];
      const int q = r0 + lrow;
      if (t0 + 63 <= r0) {
#pragma unroll
        for (int c = 0; c < 4; ++c)
#pragma unroll
          for (int j = 0; j < 4; ++j)
            p[c * 4 + j] = sc[c][j] * KS;
      } else {
#pragma unroll
        for (int c = 0; c < 4; ++c)
#pragma unroll
          for (int j = 0; j < 4; ++j) {
            int kv = t0 + c * 16 + lgrp * 4 + j;
            p[c * 4 + j] = (kv <= q) ? sc[c][j] * KS : -3.0e38f;
          }
      }

      float m8[8], m4[4];
#pragma unroll
      for (int i = 0; i < 8; ++i) m8[i] = fmaxf(p[i], p[i + 8]);
#pragma unroll
      for (int i = 0; i < 4; ++i) m4[i] = fmaxf(m8[i], m8[i + 4]);
      float mx = fmaxf(fmaxf(m4[0], m4[1]), fmaxf(m4[2], m4[3]));
      mx = fmaxf(mx, __shfl_xor(mx, 16, 64));
      mx = fmaxf(mx, __shfl_xor(mx, 32, 64));

      if (__all(mx <= m_col + 8.f)) {
        // defer: alpha == 1
      } else {
        float nm = fmaxf(m_col, mx);
        float alpha = __builtin_amdgcn_exp2f(m_col - nm);
        m_col = nm;
        float ar[4];
#pragma unroll
        for (int j = 0; j < 4; ++j)
          ar[j] = __shfl(alpha, lgrp * 4 + j, 64);
#pragma unroll
        for (int nf = 0; nf < 4; ++nf)
#pragma unroll
          for (int j = 0; j < 4; ++j)
            oacc[nf][j] *= ar[j];
        l_col *= alpha;
      }

#pragma unroll
      for (int i = 0; i < 16; ++i)
        p[i] = __builtin_amdgcn_exp2f(p[i] - m_col);
      float s8[8], s4[4];
#pragma unroll
      for (int i = 0; i < 8; ++i) s8[i] = p[i] + p[i + 8];
#pragma unroll
      for (int i = 0; i < 4; ++i) s4[i] = s8[i] + s8[i + 4];
      float rs = (s4[0] + s4[1]) + (s4[2] + s4[3]);
      rs += __shfl_xor(rs, 16, 64);
      rs += __shfl_xor(rs, 32, 64);
      l_col += rs;

#pragma unroll
      for (int c = 0; c < 4; ++c)
#pragma unroll
        for (int e = 0; e < 2; ++e) {
          union { __bf16 hh[2]; unsigned u; } pk;
          pk.hh[0] = (__bf16)p[c * 4 + 2 * e];
          pk.hh[1] = (__bf16)p[c * 4 + 2 * e + 1];
          *(unsigned*)&lds_p[wave][lrow][c * 16 + lgrp * 4 + 2 * e] = pk.u;
        }
      asm volatile("s_waitcnt lgkmcnt(0)" ::: "memory");

      bf16x8 pa0 = *(const bf16x8*)&lds_p[wave][lrow][lk];
      __builtin_amdgcn_s_setprio(1);
#pragma unroll
      for (int nf = 0; nf < 4; ++nf) {
        bf16x8 vb = *(const bf16x8*)(
            &Vs[cur][(nf * 16 + lrow) * 64 + ((lgrp ^ (lrow & 7)) * 8)]);
        oacc[nf] = __builtin_amdgcn_mfma_f32_16x16x32_bf16(pa0, vb, oacc[nf], 0, 0, 0);
      }
      __builtin_amdgcn_s_setprio(0);
      if (dmax >= 32) {
        bf16x8 pa1 = *(const bf16x8*)&lds_p[wave][lrow][32 + lk];
        __builtin_amdgcn_s_setprio(1);
#pragma unroll
        for (int nf = 0; nf < 4; ++nf) {
          bf16x8 vb = *(const bf16x8*)(
              &Vs[cur][(nf * 16 + lrow) * 64 + (((4 + lgrp) ^ (lrow & 7)) * 8)]);
          oacc[nf] = __builtin_amdgcn_mfma_f32_16x16x32_bf16(pa1, vb, oacc[nf], 0, 0, 0);
        }
        __builtin_amdgcn_s_setprio(0);
      }
    }

    *(uint4*)(&Ks[cur ^ 1][sr * 64 + dcol * 8]) = kreg;
    *(uint4*)(&Vs[cur ^ 1][sr * 64 + dcol * 8]) = vreg;
    __syncthreads();
  }

  float rlr[4];
#pragma unroll
  for (int j = 0; j < 4; ++j)
    rlr[j] = 1.0f / __shfl(l_col, lgrp * 4 + j, 64);
#pragma unroll
  for (int nf = 0; nf < 4; ++nf)
#pragma unroll
    for (int j = 0; j < 4; ++j) {
      int row = r0 + lgrp * 4 + j;
      attn_buf[(size_t)row * (NH * HD) + h * HD + nf * 16 + lrow] =
          (__bf16)(oacc[nf][j] * rlr[j]);
    }
}

extern "C" void kernel_launch(void* const* d_in, const int* in_sizes, int n_in,
                              void* d_out, int out_size, void* d_ws, size_t ws_size,
                              hipStream_t stream)
{
  const float* x  = (const float*)d_in[0];
  const float* wq = (const float*)d_in[1];
  const float* wk = (const float*)d_in[2];
  const float* wv = (const float*)d_in[3];
  const float* wo = (const float*)d_in[4];
  const float* fc = (const float*)d_in[5];
  float* out = (float*)d_out;

  char* ws = (char*)d_ws;
  __bf16* q_buf    = (__bf16*)(ws);                       //  8 MB [NH][S][HD]
  __bf16* k_buf    = (__bf16*)(ws +  8u * 1024 * 1024);   //  2 MB [NKV][S][HD]
  __bf16* v_buf    = (__bf16*)(ws + 10u * 1024 * 1024);   //  2 MB [NKV][HD][S]
  __bf16* attn_buf = (__bf16*)(ws + 12u * 1024 * 1024);   //  8 MB [S][NH*HD]
  __bf16* xb       = (__bf16*)(ws + 20u * 1024 * 1024);   //  8 MB [S][DIM]
  __bf16* wb       = (__bf16*)(ws + 28u * 1024 * 1024);   // 12 MB [3072][DIM]
  __bf16* wob      = (__bf16*)(ws + 40u * 1024 * 1024);   //  8 MB [DIM][DIM]

  cvt_xw<<<dim3(14336), 256, 0, stream>>>(x, wq, wk, wv, wo, xb, wb, wob);
  qkv_gemm<<<dim3(384), 512, 0, stream>>>(xb, wb, q_buf, k_buf, v_buf);
  rope_k<<<dim3(2048), 256, 0, stream>>>(k_buf, fc);
  attn_kernel<<<dim3(512), 512, 0, stream>>>(q_buf, k_buf, v_buf, fc, attn_buf);
  oproj_gemm<<<dim3(256), 512, 0, stream>>>(attn_buf, wob, out);
}

// Round 10
// 150.368 us; speedup vs baseline: 1.3089x; 1.0384x over previous
//
#include <hip/hip_runtime.h>
#include <hip/hip_bf16.h>

#define S_LEN 2048
#define DIM_  2048
#define NH    32
#define NKV   8
#define HD    64

typedef __bf16 bf16x8 __attribute__((ext_vector_type(8)));
typedef __bf16 bf16x4 __attribute__((ext_vector_type(4)));
typedef float  f32x4  __attribute__((ext_vector_type(4)));

#define AS_GLOBAL(p) ((const __attribute__((address_space(1))) void*)(p))
#define AS_LDS(p)    ((__attribute__((address_space(3))) void*)(p))

// ---------------- fp32 -> bf16 conversion (x, wq|wk|wv concat, wo) ----------
__global__ __launch_bounds__(256) void cvt_xw(
    const float* __restrict__ x,  const float* __restrict__ wq,
    const float* __restrict__ wk, const float* __restrict__ wv,
    const float* __restrict__ wo,
    __bf16* __restrict__ xb, __bf16* __restrict__ wb, __bf16* __restrict__ wob)
{
  size_t i = (size_t)blockIdx.x * 256 + threadIdx.x;
  const float* src; __bf16* dst; size_t off;
  if (i < 1048576)      { src = x;  dst = xb;            off = i; }
  else if (i < 2097152) { src = wq; dst = wb;            off = i - 1048576; }
  else if (i < 2359296) { src = wk; dst = wb + 4194304;  off = i - 2097152; }
  else if (i < 2621440) { src = wv; dst = wb + 5242880;  off = i - 2359296; }
  else                  { src = wo; dst = wob;           off = i - 2621440; }
  float4 f = ((const float4*)src)[off];
  bf16x4 r;
  r[0] = (__bf16)f.x; r[1] = (__bf16)f.y; r[2] = (__bf16)f.z; r[3] = (__bf16)f.w;
  ((bf16x4*)dst)[off] = r;
}

// ------- 128x64 bf16 GEMM tile, BK=32, 256 thr / 4 waves, global_load_lds ---
// m97 concurrency recipe: small blocks, >=2-3 blocks/CU so independent blocks
// hide each other's barrier drains. Wave (2x2 grid) owns 64x32 out = 4x2 frags.
#define BK 32
#define TA_ELEMS 4096   // 128*32 A tile
#define TB_ELEMS 2048   //  64*32 B tile

// 256 threads stage a 128x32 tile (8 KB): two 16B chunks each.
__device__ __forceinline__ void stage_A(
    const __bf16* __restrict__ g, int row0, int k0, int ld, __bf16* lds)
{
  const int tid = threadIdx.x;
  const int wave = tid >> 6;
#pragma unroll
  for (int iss = 0; iss < 2; ++iss) {
    int off = (iss * 256 + tid) * 16;   // byte offset in 8 KB tile
    int r = off >> 6;                   // 64 B per row (32 bf16)
    int c = (off & 63) >> 1;
    __builtin_amdgcn_global_load_lds(
        AS_GLOBAL(g + (size_t)(row0 + r) * ld + k0 + c),
        AS_LDS(lds + iss * 2048 + wave * 512),   // wave-uniform base + lane*16
        16, 0, 0);
  }
}

// 256 threads stage a 64x32 tile (4 KB): one 16B chunk each.
__device__ __forceinline__ void stage_B(
    const __bf16* __restrict__ g, int row0, int k0, int ld, __bf16* lds)
{
  const int tid = threadIdx.x;
  int off = tid * 16;
  int r = off >> 6;
  int c = (off & 63) >> 1;
  __builtin_amdgcn_global_load_lds(
      AS_GLOBAL(g + (size_t)(row0 + r) * ld + k0 + c),
      AS_LDS(lds + (tid >> 6) * 512), 16, 0, 0);
}

__device__ __forceinline__ void gemm_mainloop(
    const __bf16* __restrict__ A, const __bf16* __restrict__ B,
    int row0, int col0, int lda, int ldb, int nt,
    __bf16* As, __bf16* Bs, f32x4 acc[4][2])
{
  const int lane = threadIdx.x & 63;
  const int wave = threadIdx.x >> 6;
  const int wr = wave >> 1, wc = wave & 1;   // 2x2 wave grid
  const int fr = lane & 15, fg = lane >> 4;

  stage_A(A, row0, 0, lda, As);
  stage_B(B, col0, 0, ldb, Bs);

  for (int t = 0; t < nt; ++t) {
    const int cur = t & 1;
    if (t + 1 < nt) {
      stage_A(A, row0, (t + 1) * BK, lda, As + (cur ^ 1) * TA_ELEMS);
      stage_B(B, col0, (t + 1) * BK, ldb, Bs + (cur ^ 1) * TB_ELEMS);
    }
    __syncthreads();
    bf16x8 a[4], b[2];
#pragma unroll
    for (int mi = 0; mi < 4; ++mi)
      a[mi] = *(const bf16x8*)(As + cur * TA_ELEMS + (wr * 64 + mi * 16 + fr) * 32 + fg * 8);
#pragma unroll
    for (int ni = 0; ni < 2; ++ni)
      b[ni] = *(const bf16x8*)(Bs + cur * TB_ELEMS + (wc * 32 + ni * 16 + fr) * 32 + fg * 8);
#pragma unroll
    for (int mi = 0; mi < 4; ++mi)
#pragma unroll
      for (int ni = 0; ni < 2; ++ni)
        acc[mi][ni] = __builtin_amdgcn_mfma_f32_16x16x32_bf16(a[mi], b[ni], acc[mi][ni], 0, 0, 0);
    __syncthreads();
  }
}

// ---------------- QKV projection (bf16, 768 blocks = 3/CU) ------------------
// XCD swizzle: per XCD 6 col-panels (64 cols) x 16 row-tiles -> B slice 1.5 MB
// L2-resident; A streams via L3.
__global__ __launch_bounds__(256) void qkv_gemm(
    const __bf16* __restrict__ xb, const __bf16* __restrict__ wb,
    __bf16* __restrict__ q_buf, __bf16* __restrict__ k_buf, __bf16* __restrict__ v_buf)
{
  __shared__ __bf16 As[2 * TA_ELEMS];
  __shared__ __bf16 Bs[2 * TB_ELEMS];
  const int lane = threadIdx.x & 63;
  const int wave = threadIdx.x >> 6;
  const int wr = wave >> 1, wc = wave & 1;
  const int fr = lane & 15, fg = lane >> 4;

  const int lid = blockIdx.x;        // 0..767
  const int xcd = lid & 7;
  const int i   = lid >> 3;          // 0..95
  const int row0 = (i & 15) * 128;
  const int col0 = (xcd * 6 + (i >> 4)) * 64;

  f32x4 acc[4][2] = {};
  gemm_mainloop(xb, wb, row0, col0, DIM_, DIM_, DIM_ / BK, As, Bs, acc);

  const int rowg0 = row0 + wr * 64;
  const int colg0 = col0 + wc * 32;
#pragma unroll
  for (int mi = 0; mi < 4; ++mi) {
#pragma unroll
    for (int ni = 0; ni < 2; ++ni) {
#pragma unroll
      for (int j = 0; j < 4; ++j) {
        int row = rowg0 + mi * 16 + fg * 4 + j;
        int col = colg0 + ni * 16 + fr;
        float v = acc[mi][ni][j];
        if (col < 2048) {
          int h = col >> 6, d = col & 63;
          q_buf[((size_t)h * S_LEN + row) * HD + d] = (__bf16)v;
        } else if (col < 2560) {
          int c = col - 2048, g = c >> 6, d = c & 63;
          k_buf[((size_t)g * S_LEN + row) * HD + d] = (__bf16)v;
        } else {
          int c = col - 2560, g = c >> 6, d = c & 63;
          v_buf[((size_t)g * HD + d) * S_LEN + row] = (__bf16)v;  // transposed
        }
      }
    }
  }
}

// ---------------- Output projection (bf16, 512 blocks = 2/CU) ---------------
__global__ __launch_bounds__(256) void oproj_gemm(
    const __bf16* __restrict__ attn_buf, const __bf16* __restrict__ wob,
    float* __restrict__ out)
{
  __shared__ __bf16 As[2 * TA_ELEMS];
  __shared__ __bf16 Bs[2 * TB_ELEMS];
  const int lane = threadIdx.x & 63;
  const int wave = threadIdx.x >> 6;
  const int wr = wave >> 1, wc = wave & 1;
  const int fr = lane & 15, fg = lane >> 4;

  const int lid = blockIdx.x;        // 0..511
  const int xcd = lid & 7;
  const int i   = lid >> 3;          // 0..63
  const int row0 = (i & 15) * 128;
  const int col0 = (xcd * 4 + (i >> 4)) * 64;

  f32x4 acc[4][2] = {};
  gemm_mainloop(attn_buf, wob, row0, col0, DIM_, DIM_, DIM_ / BK, As, Bs, acc);

  const int rowg0 = row0 + wr * 64;
  const int colg0 = col0 + wc * 32;
#pragma unroll
  for (int mi = 0; mi < 4; ++mi)
#pragma unroll
    for (int ni = 0; ni < 2; ++ni)
#pragma unroll
      for (int j = 0; j < 4; ++j) {
        int row = rowg0 + mi * 16 + fg * 4 + j;
        int col = colg0 + ni * 16 + fr;
        out[(size_t)row * DIM_ + col] = acc[mi][ni][j];
      }
}

// ---------------- RoPE on K only (in place, bf16); Q fused into attn --------
__global__ __launch_bounds__(256) void rope_k(
    __bf16* __restrict__ k_buf, const float* __restrict__ fc)
{
  int idx = blockIdx.x * 256 + threadIdx.x;
  int i    = idx & 31;
  int sp   = (idx >> 5) & (S_LEN - 1);
  int g    = idx >> 16;
  __bf16* buf = k_buf + ((size_t)g * S_LEN + sp) * HD;
  float c = fc[(sp * 32 + i) * 2 + 0];
  float s = fc[(sp * 32 + i) * 2 + 1];
  float x1 = (float)buf[2 * i], x2 = (float)buf[2 * i + 1];
  buf[2 * i + 0] = (__bf16)(x1 * c - x2 * s);
  buf[2 * i + 1] = (__bf16)(x1 * s + x2 * c);
}

// ---------------- Flash attention (causal, GQA, swapped-QK, shared KV) ------
// 1-D grid 512, PAIRED dispatch: blocks 0..255 = long q-tiles, 256..511 short.
__global__ __launch_bounds__(512) void attn_kernel(
    const __bf16* __restrict__ q_buf, const __bf16* __restrict__ k_buf,
    const __bf16* __restrict__ v_buf, const float* __restrict__ fc,
    __bf16* __restrict__ attn_buf)
{
  __shared__ __align__(16) __bf16 Ks[2][64 * 64];   // 2 x 8 KB
  __shared__ __align__(16) __bf16 Vs[2][64 * 64];   // 2 x 8 KB (V^T: [d][kv])
  __shared__ __align__(16) __bf16 lds_p[8][16][72]; // per-wave P slab

  const int tid  = threadIdx.x;
  const int lane = tid & 63;
  const int wave = tid >> 6;
  const int n = blockIdx.x;
  const int qt = (n < 256) ? (15 - (n >> 5)) : ((n - 256) >> 5);
  const int h  = n & 31;
  const int g = h >> 2;             // NREP = 4
  const int r0 = qt * 128 + wave * 16;
  const int lrow = lane & 15;
  const int lgrp = lane >> 4;
  const int lk = lgrp * 8;

  const __bf16* qh = q_buf + (size_t)h * S_LEN * HD;
  const __bf16* kh = k_buf + (size_t)g * S_LEN * HD;
  const __bf16* vh = v_buf + (size_t)g * HD * S_LEN;

  const int sr   = tid >> 3;            // staging row 0..63
  const int scol = tid & 7;             // source 16B chunk
  const int dcol = scol ^ (sr & 7);     // swizzled dest chunk

  // ---- load Q fragment + apply RoPE in-register ----
  bf16x8 qa[2];
  const float* fcrow = fc + (size_t)(r0 + lrow) * 64;
#pragma unroll
  for (int kk = 0; kk < 2; ++kk) {
    qa[kk] = *(const bf16x8*)(qh + (size_t)(r0 + lrow) * HD + kk * 32 + lk);
    float4 cs0 = *(const float4*)(fcrow + (kk * 16 + lgrp * 4) * 2);
    float4 cs1 = *(const float4*)(fcrow + (kk * 16 + lgrp * 4) * 2 + 4);
    float cc[4] = {cs0.x, cs0.z, cs1.x, cs1.z};
    float ss[4] = {cs0.y, cs0.w, cs1.y, cs1.w};
#pragma unroll
    for (int pr = 0; pr < 4; ++pr) {
      float x1 = (float)qa[kk][2 * pr], x2 = (float)qa[kk][2 * pr + 1];
      qa[kk][2 * pr]     = (__bf16)(x1 * cc[pr] - x2 * ss[pr]);
      qa[kk][2 * pr + 1] = (__bf16)(x1 * ss[pr] + x2 * cc[pr]);
    }
  }

  const float KS = 0.125f * 1.44269504088896f;  // scale * log2(e)
  float m_col = -3.0e38f, l_col = 0.f;
  f32x4 oacc[4] = {};

  const int nt = 2 * qt + 2;

  {
    uint4 k0 = *(const uint4*)(kh + (size_t)sr * HD + scol * 8);
    uint4 v0 = *(const uint4*)(vh + (size_t)sr * S_LEN + scol * 8);
    *(uint4*)(&Ks[0][sr * 64 + dcol * 8]) = k0;
    *(uint4*)(&Vs[0][sr * 64 + dcol * 8]) = v0;
  }
  __syncthreads();

  for (int t = 0; t < nt; ++t) {
    const int cur = t & 1;
    const int t0 = t * 64;

    const int tn0 = (t + 1 < nt ? t + 1 : t) * 64;
    uint4 kreg = *(const uint4*)(kh + (size_t)(tn0 + sr) * HD + scol * 8);
    uint4 vreg = *(const uint4*)(vh + (size_t)sr * S_LEN + tn0 + scol * 8);

    const int dmax = r0 + 15 - t0;
    if (dmax >= 0) {
      f32x4 sc[4] = {};
      const int cmax = dmax >> 4;
      __builtin_amdgcn_s_setprio(1);
#pragma unroll
      for (int c = 0; c < 4; ++c) {
        if (c <= cmax) {
#pragma unroll
          for (int kk = 0; kk < 2; ++kk) {
            bf16x8 ka = *(const bf16x8*)(
                &Ks[cur][(c * 16 + lrow) * 64 + (((kk * 4 + lgrp) ^ (lrow & 7)) * 8)]);
            sc[c] = __builtin_amdgcn_mfma_f32_16x16x32_bf16(ka, qa[kk], sc[c], 0, 0, 0);
          }
        }
      }
      __builtin_amdgcn_s_setprio(0);

      float p[16];
      const int q = r0 + lrow;
      if (t0 + 63 <= r0) {
#pragma unroll
        for (int c = 0; c < 4; ++c)
#pragma unroll
          for (int j = 0; j < 4; ++j)
            p[c * 4 + j] = sc[c][j] * KS;
      } else {
#pragma unroll
        for (int c = 0; c < 4; ++c)
#pragma unroll
          for (int j = 0; j < 4; ++j) {
            int kv = t0 + c * 16 + lgrp * 4 + j;
            p[c * 4 + j] = (kv <= q) ? sc[c][j] * KS : -3.0e38f;
          }
      }

      float m8[8], m4[4];
#pragma unroll
      for (int i = 0; i < 8; ++i) m8[i] = fmaxf(p[i], p[i + 8]);
#pragma unroll
      for (int i = 0; i < 4; ++i) m4[i] = fmaxf(m8[i], m8[i + 4]);
      float mx = fmaxf(fmaxf(m4[0], m4[1]), fmaxf(m4[2], m4[3]));
      mx = fmaxf(mx, __shfl_xor(mx, 16, 64));
      mx = fmaxf(mx, __shfl_xor(mx, 32, 64));

      if (__all(mx <= m_col + 8.f)) {
        // defer: alpha == 1
      } else {
        float nm = fmaxf(m_col, mx);
        float alpha = __builtin_amdgcn_exp2f(m_col - nm);
        m_col = nm;
        float ar[4];
#pragma unroll
        for (int j = 0; j < 4; ++j)
          ar[j] = __shfl(alpha, lgrp * 4 + j, 64);
#pragma unroll
        for (int nf = 0; nf < 4; ++nf)
#pragma unroll
          for (int j = 0; j < 4; ++j)
            oacc[nf][j] *= ar[j];
        l_col *= alpha;
      }

#pragma unroll
      for (int i = 0; i < 16; ++i)
        p[i] = __builtin_amdgcn_exp2f(p[i] - m_col);
      float s8[8], s4[4];
#pragma unroll
      for (int i = 0; i < 8; ++i) s8[i] = p[i] + p[i + 8];
#pragma unroll
      for (int i = 0; i < 4; ++i) s4[i] = s8[i] + s8[i + 4];
      float rs = (s4[0] + s4[1]) + (s4[2] + s4[3]);
      rs += __shfl_xor(rs, 16, 64);
      rs += __shfl_xor(rs, 32, 64);
      l_col += rs;

#pragma unroll
      for (int c = 0; c < 4; ++c)
#pragma unroll
        for (int e = 0; e < 2; ++e) {
          union { __bf16 hh[2]; unsigned u; } pk;
          pk.hh[0] = (__bf16)p[c * 4 + 2 * e];
          pk.hh[1] = (__bf16)p[c * 4 + 2 * e + 1];
          *(unsigned*)&lds_p[wave][lrow][c * 16 + lgrp * 4 + 2 * e] = pk.u;
        }
      asm volatile("s_waitcnt lgkmcnt(0)" ::: "memory");

      bf16x8 pa0 = *(const bf16x8*)&lds_p[wave][lrow][lk];
      __builtin_amdgcn_s_setprio(1);
#pragma unroll
      for (int nf = 0; nf < 4; ++nf) {
        bf16x8 vb = *(const bf16x8*)(
            &Vs[cur][(nf * 16 + lrow) * 64 + ((lgrp ^ (lrow & 7)) * 8)]);
        oacc[nf] = __builtin_amdgcn_mfma_f32_16x16x32_bf16(pa0, vb, oacc[nf], 0, 0, 0);
      }
      __builtin_amdgcn_s_setprio(0);
      if (dmax >= 32) {
        bf16x8 pa1 = *(const bf16x8*)&lds_p[wave][lrow][32 + lk];
        __builtin_amdgcn_s_setprio(1);
#pragma unroll
        for (int nf = 0; nf < 4; ++nf) {
          bf16x8 vb = *(const bf16x8*)(
              &Vs[cur][(nf * 16 + lrow) * 64 + (((4 + lgrp) ^ (lrow & 7)) * 8)]);
          oacc[nf] = __builtin_amdgcn_mfma_f32_16x16x32_bf16(pa1, vb, oacc[nf], 0, 0, 0);
        }
        __builtin_amdgcn_s_setprio(0);
      }
    }

    *(uint4*)(&Ks[cur ^ 1][sr * 64 + dcol * 8]) = kreg;
    *(uint4*)(&Vs[cur ^ 1][sr * 64 + dcol * 8]) = vreg;
    __syncthreads();
  }

  float rlr[4];
#pragma unroll
  for (int j = 0; j < 4; ++j)
    rlr[j] = 1.0f / __shfl(l_col, lgrp * 4 + j, 64);
#pragma unroll
  for (int nf = 0; nf < 4; ++nf)
#pragma unroll
    for (int j = 0; j < 4; ++j) {
      int row = r0 + lgrp * 4 + j;
      attn_buf[(size_t)row * (NH * HD) + h * HD + nf * 16 + lrow] =
          (__bf16)(oacc[nf][j] * rlr[j]);
    }
}

extern "C" void kernel_launch(void* const* d_in, const int* in_sizes, int n_in,
                              void* d_out, int out_size, void* d_ws, size_t ws_size,
                              hipStream_t stream)
{
  const float* x  = (const float*)d_in[0];
  const float* wq = (const float*)d_in[1];
  const float* wk = (const float*)d_in[2];
  const float* wv = (const float*)d_in[3];
  const float* wo = (const float*)d_in[4];
  const float* fc = (const float*)d_in[5];
  float* out = (float*)d_out;

  char* ws = (char*)d_ws;
  __bf16* q_buf    = (__bf16*)(ws);                       //  8 MB [NH][S][HD]
  __bf16* k_buf    = (__bf16*)(ws +  8u * 1024 * 1024);   //  2 MB [NKV][S][HD]
  __bf16* v_buf    = (__bf16*)(ws + 10u * 1024 * 1024);   //  2 MB [NKV][HD][S]
  __bf16* attn_buf = (__bf16*)(ws + 12u * 1024 * 1024);   //  8 MB [S][NH*HD]
  __bf16* xb       = (__bf16*)(ws + 20u * 1024 * 1024);   //  8 MB [S][DIM]
  __bf16* wb       = (__bf16*)(ws + 28u * 1024 * 1024);   // 12 MB [3072][DIM]
  __bf16* wob      = (__bf16*)(ws + 40u * 1024 * 1024);   //  8 MB [DIM][DIM]

  cvt_xw<<<dim3(14336), 256, 0, stream>>>(x, wq, wk, wv, wo, xb, wb, wob);
  qkv_gemm<<<dim3(768), 256, 0, stream>>>(xb, wb, q_buf, k_buf, v_buf);
  rope_k<<<dim3(2048), 256, 0, stream>>>(k_buf, fc);
  attn_kernel<<<dim3(512), 512, 0, stream>>>(q_buf, k_buf, v_buf, fc, attn_buf);
  oproj_gemm<<<dim3(512), 256, 0, stream>>>(attn_buf, wob, out);
}